// Round 1
// 614.767 us; speedup vs baseline: 2.0141x; 2.0141x over previous
//
#include <hip/hip_runtime.h>
#include <math.h>

// Problem constants (fixed by setup_inputs)
constexpr int B_ = 8;
constexpr int N_ = 2048;
constexpr int D_ = 256;
constexpr int H_ = 16;
constexpr int K_ = 8;
constexpr int CAND = 32;   // candidate pool for exact re-ranking

constexpr int BM = 128;    // tile rows (q and p)
constexpr int BK = 64;     // k chunk per stage (2 MFMA K-steps)

typedef __bf16 bf16x8 __attribute__((ext_vector_type(8)));
typedef float  f32x4  __attribute__((ext_vector_type(4)));

// address-space-qualified pointers for global_load_lds
typedef __attribute__((address_space(3))) unsigned int       lds_u32_t;
typedef __attribute__((address_space(1))) const unsigned int glb_u32_t;

__device__ __forceinline__ void g2l16(const void* g, void* l) {
    // 16B direct global->LDS (dest = wave-uniform base + lane*16)
    __builtin_amdgcn_global_load_lds((glb_u32_t*)g, (lds_u32_t*)l, 16, 0, 0);
}

// ---------------------------------------------------------------------------
// split fp32*scale -> packed bf16 hi (truncated) + bf16 lo (residual, trunc)
// (identical numerics to the verified kernel)
// ---------------------------------------------------------------------------
__device__ inline void split4(float4 v, float s, uint2& hi, uint2& lo) {
    float a = v.x * s, b = v.y * s, c = v.z * s, d = v.w * s;
    unsigned ua = __float_as_uint(a), ub = __float_as_uint(b);
    unsigned uc = __float_as_uint(c), ud = __float_as_uint(d);
    unsigned ha = ua & 0xFFFF0000u, hb = ub & 0xFFFF0000u;
    unsigned hc = uc & 0xFFFF0000u, hd = ud & 0xFFFF0000u;
    hi.x = (ha >> 16) | hb;
    hi.y = (hc >> 16) | hd;
    float ra = a - __uint_as_float(ha), rb = b - __uint_as_float(hb);
    float rc = c - __uint_as_float(hc), rd = d - __uint_as_float(hd);
    lo.x = (__float_as_uint(ra) >> 16) | (__float_as_uint(rb) & 0xFFFF0000u);
    lo.y = (__float_as_uint(rc) >> 16) | (__float_as_uint(rd) & 0xFFFF0000u);
}

// ---------------------------------------------------------------------------
// Kernel 1 (prep): fp32 -> normalized bf16 hi/lo, stored tile-panel-major and
// PRE-SWIZZLED so that a linear global_load_lds copy yields a bank-conflict-
// free LDS layout (m173 pattern: swizzle the source, keep LDS linear).
//
// Layout: per matrix, tiles of [128 rows][64 k-elems] (=16 KiB). Tile index =
// (row/128)*4 + (k/64). Within a tile: row-major rows of 128 B; each row's
// eight 16 B slots are XOR-permuted: slot' = slot ^ (row & 7).
// One wave per row; lane holds 4 consecutive k-elems.
// ---------------------------------------------------------------------------
__global__ __launch_bounds__(256)
void prep_kernel(const float* __restrict__ f1, const float* __restrict__ f2,
                 unsigned short* __restrict__ s1h, unsigned short* __restrict__ s1l,
                 unsigned short* __restrict__ s2h, unsigned short* __restrict__ s2l) {
    int gid  = blockIdx.x * blockDim.x + threadIdx.x;
    int wave = gid >> 6;
    int lane = gid & 63;
    if (wave >= 2 * B_ * N_) return;
    bool is1 = wave < B_ * N_;
    int r = is1 ? wave : wave - B_ * N_;

    const float* src = (is1 ? f1 : f2) + (size_t)r * D_;
    float4 v = *(const float4*)(src + lane * 4);
    float ss = v.x * v.x + v.y * v.y + v.z * v.z + v.w * v.w;
#pragma unroll
    for (int off = 32; off > 0; off >>= 1) ss += __shfl_xor(ss, off, 64);
    float inv = 1.0f / (sqrtf(ss) + 1e-8f);

    uint2 hi, lo;
    split4(v, inv, hi, lo);

    int panel = r >> 7, rloc = r & 127;
    int slot  = lane >> 1;                 // 16B slot index 0..31
    int chunk = slot >> 3;                 // which 64-elem k-chunk (tile)
    int sl    = (slot & 7) ^ (rloc & 7);   // swizzled slot within 128B row
    int half  = lane & 1;
    size_t idx = ((size_t)(panel * 4 + chunk) << 13)   // tile * 8192 ushorts
               + (size_t)rloc * 64 + sl * 8 + half * 4;
    *(uint2*)&(is1 ? s1h : s2h)[idx] = hi;
    *(uint2*)&(is1 ? s1l : s2l)[idx] = lo;
}

// ---------------------------------------------------------------------------
// Kernel 2: MFMA cosine-sim GEMM (bf16x3 split precision) + coord dist + MLP.
// m97 structure: global_load_lds(16B) staging of pre-converted bf16 panels,
// BK=64, linear LDS + source-baked XOR swizzle, 96 MFMA per wave per K-step.
// Numerics identical to the previously verified kernel (same split, same
// 3-term MFMA sequence in the same K=32 order, same epilogue).
// ---------------------------------------------------------------------------
__global__ __launch_bounds__(256, 2)
void gemm_mlp_kernel(const unsigned short* __restrict__ aH0,  // f2 hi (A side, q)
                     const unsigned short* __restrict__ aL0,  // f2 lo
                     const unsigned short* __restrict__ bH0,  // f1 hi (B side, p)
                     const unsigned short* __restrict__ bL0,  // f1 lo
                     const float* __restrict__ pc, const float* __restrict__ qc,
                     const float* __restrict__ pW1, const float* __restrict__ pb1,
                     const float* __restrict__ pW2, const float* __restrict__ pb2,
                     float* __restrict__ w_out) {
    // 4 linear tiles: Ahi | Alo | Bhi | Blo, 16 KiB each = 64 KiB
    __shared__ unsigned short ldsbuf[4 * 8192];

    int tid = threadIdx.x;
    // bijective XCD chunking swizzle within each z-slice (256 blocks, 256%8==0):
    // dispatch id l -> l' so each XCD gets 32 contiguous tile ids.
    int l  = blockIdx.x + (blockIdx.y << 4);
    int ls = ((l & 7) << 5) | (l >> 3);
    int pBase = (ls & 15) * BM;
    int qBase = (ls >> 4) * BM;
    int b = blockIdx.z;

    int lane = tid & 63;
    int wv   = tid >> 6;
    int wq = (wv >> 1) * 64;
    int wp = (wv & 1) * 64;
    int fr = lane & 15;
    int kg = lane >> 4;

    // tile-index bases (tiles are 8192 ushorts = 16384 B)
    const int Apanel = ((b * N_ + qBase) >> 7) * 4;
    const int Bpanel = ((b * N_ + pBase) >> 7) * 4;

    char* ldsB = (char*)&ldsbuf[0];
    int soff = (wv << 10) + (lane << 4);   // per-lane global byte offset
    int doff = (wv << 10);                 // wave-uniform LDS byte offset

    f32x4 acc[4][4] = {};

#pragma unroll
    for (int c = 0; c < 4; c++) {          // 4 K-chunks of 64
        __syncthreads();                   // previous compute done reading LDS
        const char* aH = (const char*)aH0 + ((size_t)(Apanel + c) << 14);
        const char* aL = (const char*)aL0 + ((size_t)(Apanel + c) << 14);
        const char* bH = (const char*)bH0 + ((size_t)(Bpanel + c) << 14);
        const char* bL = (const char*)bL0 + ((size_t)(Bpanel + c) << 14);
#pragma unroll
        for (int i = 0; i < 4; i++) {      // 4 issues/wave fill 16 KiB/tile
            int o = (i << 12);
            g2l16(aH + o + soff, ldsB + 0     + o + doff);
            g2l16(aL + o + soff, ldsB + 16384 + o + doff);
            g2l16(bH + o + soff, ldsB + 32768 + o + doff);
            g2l16(bL + o + soff, ldsB + 49152 + o + doff);
        }
        __syncthreads();                   // compiler drains vmcnt before barrier

#pragma unroll
        for (int ks = 0; ks < 2; ks++) {   // two K=32 MFMA steps per chunk
            bf16x8 ah[4], al[4], bh[4], bl[4];
#pragma unroll
            for (int t = 0; t < 4; t++) {
                int ra = (wq + t * 16 + fr) * 128;
                int rb = (wp + t * 16 + fr) * 128;
                int cw = ((ks * 4 + kg) ^ (fr & 7)) << 4;  // swizzled 16B slot
                ah[t] = *(const bf16x8*)(ldsB + 0     + ra + cw);
                al[t] = *(const bf16x8*)(ldsB + 16384 + ra + cw);
                bh[t] = *(const bf16x8*)(ldsB + 32768 + rb + cw);
                bl[t] = *(const bf16x8*)(ldsB + 49152 + rb + cw);
            }
#pragma unroll
            for (int qt = 0; qt < 4; qt++) {
#pragma unroll
                for (int pt = 0; pt < 4; pt++) {
                    acc[qt][pt] = __builtin_amdgcn_mfma_f32_16x16x32_bf16(
                        ah[qt], bh[pt], acc[qt][pt], 0, 0, 0);
                    acc[qt][pt] = __builtin_amdgcn_mfma_f32_16x16x32_bf16(
                        ah[qt], bl[pt], acc[qt][pt], 0, 0, 0);
                    acc[qt][pt] = __builtin_amdgcn_mfma_f32_16x16x32_bf16(
                        al[qt], bh[pt], acc[qt][pt], 0, 0, 0);
                }
            }
        }
    }

    // ---------------- epilogue: coord term + MLP + store -------------------
    float px[4], py[4], pz[4], pn2[4];
    int pg[4];
#pragma unroll
    for (int pt = 0; pt < 4; pt++) {
        int p = pBase + wp + pt * 16 + fr;
        pg[pt] = p;
        const float* pp = pc + ((size_t)(b * N_ + p)) * 3;
        px[pt] = pp[0]; py[pt] = pp[1]; pz[pt] = pp[2];
        pn2[pt] = px[pt] * px[pt] + py[pt] * py[pt] + pz[pt] * pz[pt];
    }
#pragma unroll
    for (int qt = 0; qt < 4; qt++) {
        float qx[4], qy[4], qz[4], qq2[4];
        int q0 = qBase + wq + qt * 16 + kg * 4;
#pragma unroll
        for (int r = 0; r < 4; r++) {
            const float* qp = qc + ((size_t)(b * N_ + q0 + r)) * 3;
            qx[r] = qp[0]; qy[r] = qp[1]; qz[r] = qp[2];
            qq2[r] = qx[r] * qx[r] + qy[r] * qy[r] + qz[r] * qz[r];
        }
#pragma unroll
        for (int pt = 0; pt < 4; pt++) {
            f32x4 cval = acc[qt][pt];
#pragma unroll
            for (int r = 0; r < 4; r++) {
                float w1v = cval[r];
                float d2 = qq2[r] + pn2[pt]
                         - 2.f * (qx[r] * px[pt] + qy[r] * py[pt] + qz[r] * pz[pt]);
                float w2v = -fmaxf(d2, 0.f);
                float out = pb2[0];
#pragma unroll
                for (int h = 0; h < H_; h++) {
                    float t = pW1[2 * h] * w1v + pW1[2 * h + 1] * w2v + pb1[h];
                    out += pW2[h] * fmaxf(t, 0.f);
                }
                w_out[((size_t)(b * N_ + q0 + r)) * N_ + pg[pt]] = out;
            }
        }
    }
}

// ---------------------------------------------------------------------------
// Kernel 3: approx top-32 candidates -> exact fp64 rescore (parallel: 8
// groups of 8 lanes rescore 8 candidates per round, 4 rounds) -> exact top-8
// + softmax + gather + pool. One wave per (b,q) row, 4 rows per block.
// (unchanged from verified kernel)
// ---------------------------------------------------------------------------
__global__ __launch_bounds__(256)
void topk_kernel(const float* __restrict__ w, const float* __restrict__ f1,
                 const float* __restrict__ f2,
                 const float* __restrict__ pc, const float* __restrict__ qc,
                 const float* __restrict__ pW1, const float* __restrict__ pb1,
                 const float* __restrict__ pW2, const float* __restrict__ pb2,
                 float* __restrict__ f_out, float* __restrict__ idx_out) {
    __shared__ int s_cand[4][CAND];

    int tid  = threadIdx.x;
    int wix  = tid >> 6;
    int lane = tid & 63;
    int row  = blockIdx.x * 4 + wix;          // grid is exact: row < B_*N_
    int b    = row >> 11;
    const float* wrow = w + (size_t)row * N_;

    // ---- phase 1: per-lane sorted top-8 scan of approx scores ----
    float tv[K_];
    int   ti[K_];
#pragma unroll
    for (int s = 0; s < K_; s++) { tv[s] = -INFINITY; ti[s] = 0x7fffffff; }
    for (int j = 0; j < N_ / 256; j++) {
        float4 v4 = *(const float4*)(wrow + lane * 4 + j * 256);
        float vv[4] = {v4.x, v4.y, v4.z, v4.w};
#pragma unroll
        for (int c = 0; c < 4; c++) {
            float v = vv[c];
            if (v > tv[K_ - 1]) {
                int idx = lane * 4 + j * 256 + c;
                tv[K_ - 1] = v; ti[K_ - 1] = idx;
#pragma unroll
                for (int s = K_ - 1; s > 0; s--) {
                    if (tv[s] > tv[s - 1]) {
                        float tf = tv[s]; tv[s] = tv[s - 1]; tv[s - 1] = tf;
                        int tn = ti[s]; ti[s] = ti[s - 1]; ti[s - 1] = tn;
                    }
                }
            }
        }
    }

    // ---- phase 2: pop 32 wave-wide candidates (approx order) -> LDS ----
#pragma unroll
    for (int r = 0; r < CAND; r++) {
        float bv = tv[0];
        int   bi = ti[0];
#pragma unroll
        for (int off = 1; off < 64; off <<= 1) {
            float ov = __shfl_xor(bv, off, 64);
            int   oi = __shfl_xor(bi, off, 64);
            if (ov > bv || (ov == bv && oi < bi)) { bv = ov; bi = oi; }
        }
        if (lane == 0) s_cand[wix][r] = bi;
        if (ti[0] == bi) {
#pragma unroll
            for (int s = 0; s < K_ - 1; s++) { tv[s] = tv[s + 1]; ti[s] = ti[s + 1]; }
            tv[K_ - 1] = -INFINITY; ti[K_ - 1] = 0x7fffffff;
        }
    }
    __syncthreads();

    // ---- phase 3: parallel exact fp64 rescore ----
    int sl = lane & 7;
    int gr = lane >> 3;
    const float* f2r = f2 + (size_t)row * D_ + sl * 32;
    float4 a4[8];
#pragma unroll
    for (int t = 0; t < 8; t++) a4[t] = *(const float4*)(f2r + t * 4);

    double daa = 0.0;
#pragma unroll
    for (int t = 0; t < 8; t++) {
        daa += (double)a4[t].x * (double)a4[t].x;
        daa += (double)a4[t].y * (double)a4[t].y;
        daa += (double)a4[t].z * (double)a4[t].z;
        daa += (double)a4[t].w * (double)a4[t].w;
    }
#pragma unroll
    for (int off = 1; off < 8; off <<= 1) daa += __shfl_xor(daa, off, 64);
    double inv_a = 1.0 / (sqrt(daa) + 1e-8);

    double mydab = 0.0, mydbb = 0.0;
    int myci = 0x7fffffff;
#pragma unroll
    for (int r = 0; r < 4; r++) {
        int cj = s_cand[wix][8 * r + gr];
        const float* f1r = f1 + ((size_t)(b * N_ + cj)) * D_ + sl * 32;
        double sA = 0.0, sB = 0.0;
#pragma unroll
        for (int t = 0; t < 8; t++) {
            float4 b4 = *(const float4*)(f1r + t * 4);
            double b0 = b4.x, b1 = b4.y, b2 = b4.z, b3 = b4.w;
            sA += (double)a4[t].x * b0; sB += b0 * b0;
            sA += (double)a4[t].y * b1; sB += b1 * b1;
            sA += (double)a4[t].z * b2; sB += b2 * b2;
            sA += (double)a4[t].w * b3; sB += b3 * b3;
        }
#pragma unroll
        for (int off = 1; off < 8; off <<= 1) {
            sA += __shfl_xor(sA, off, 64);
            sB += __shfl_xor(sB, off, 64);
        }
        if (sl == r) { mydab = sA; mydbb = sB; myci = cj; }
    }

    double ex = -INFINITY;
    int    ei = 0x7fffffff;
    if (sl < 4) {
        ei = myci;
        double w1d = mydab * inv_a * (1.0 / (sqrt(mydbb) + 1e-8));
        const float* qp = qc + (size_t)row * 3;
        double qx = qp[0], qy = qp[1], qz = qp[2];
        const float* pp = pc + ((size_t)(b * N_ + myci)) * 3;
        double px = pp[0], py = pp[1], pz = pp[2];
        double d2 = (qx * qx + qy * qy + qz * qz) + (px * px + py * py + pz * pz)
                  - 2.0 * (qx * px + qy * py + qz * pz);
        double w2d = -fmax(d2, 0.0);
        double out = (double)pb2[0];
#pragma unroll
        for (int h = 0; h < H_; h++) {
            double t = (double)pW1[2 * h] * w1d + (double)pW1[2 * h + 1] * w2d
                     + (double)pb1[h];
            out += (double)pW2[h] * fmax(t, 0.0);
        }
        ex = out;
    }

    // ---- phase 4: exact top-8 over 32 scorer lanes (desc, smaller idx tie) ----
    double outv[K_];
    int    outi[K_];
#pragma unroll
    for (int r = 0; r < K_; r++) {
        double bv = ex;
        int    bi = ei;
#pragma unroll
        for (int off = 1; off < 64; off <<= 1) {
            double ov = __shfl_xor(bv, off, 64);
            int    oi = __shfl_xor(bi, off, 64);
            if (ov > bv || (ov == bv && oi < bi)) { bv = ov; bi = oi; }
        }
        outv[r] = bv; outi[r] = bi;
        if (ei == bi) ex = -INFINITY;   // owning lane retires its candidate
    }

    // ---- phase 5: softmax + gather + pool + write ----
    float m = (float)outv[0];
    float e[K_], s = 0.f;
#pragma unroll
    for (int r = 0; r < K_; r++) { e[r] = expf((float)outv[r] - m); s += e[r]; }
    float inv_s = 1.f / s;

    const float* f1b = f1 + ((size_t)b * N_) * D_;
    size_t obase = (size_t)row * (2 * D_);
#pragma unroll
    for (int jd = 0; jd < D_ / 64; jd++) {
        int d = lane + 64 * jd;
        float accv = 0.f, mx = -INFINITY;
#pragma unroll
        for (int r = 0; r < K_; r++) {
            float x = f1b[(size_t)outi[r] * D_ + d];
            accv += (e[r] * inv_s) * x;
            mx = fmaxf(mx, x);
        }
        f_out[obase + d]      = accv;
        f_out[obase + D_ + d] = mx;
    }
    if (lane == 0) {
#pragma unroll
        for (int r = 0; r < K_; r++) idx_out[(size_t)row * K_ + r] = (float)outi[r];
    }
}

// ---------------------------------------------------------------------------
extern "C" void kernel_launch(void* const* d_in, const int* in_sizes, int n_in,
                              void* d_out, int out_size, void* d_ws, size_t ws_size,
                              hipStream_t stream) {
    const float* f1 = (const float*)d_in[0];
    const float* f2 = (const float*)d_in[1];
    const float* pc = (const float*)d_in[2];
    const float* qc = (const float*)d_in[3];
    const float* W1 = (const float*)d_in[4];
    const float* b1 = (const float*)d_in[5];
    const float* W2 = (const float*)d_in[6];
    const float* b2 = (const float*)d_in[7];

    float* out     = (float*)d_out;
    float* f_out   = out;                                   // [B,N,2D]
    float* idx_out = f_out + (size_t)B_ * N_ * 2 * D_;      // [B,N,K] as float
    float* w_out   = idx_out + (size_t)B_ * N_ * K_;        // [B,N,N]

    // Scratch bf16 hi/lo panels live in the f_out region (33,554,432 B,
    // exactly 4 arrays of B*N*D ushorts). f_out is only written by
    // topk_kernel afterwards, so this is safe under stream ordering.
    unsigned short* s1h = (unsigned short*)f_out;           // f1 hi (B side)
    unsigned short* s1l = s1h + (size_t)B_ * N_ * D_;       // f1 lo
    unsigned short* s2h = s1l + (size_t)B_ * N_ * D_;       // f2 hi (A side)
    unsigned short* s2l = s2h + (size_t)B_ * N_ * D_;       // f2 lo

    prep_kernel<<<(2 * B_ * N_) / 4, 256, 0, stream>>>(f1, f2, s1h, s1l, s2h, s2l);

    dim3 g2(N_ / BM, N_ / BM, B_);
    gemm_mlp_kernel<<<g2, 256, 0, stream>>>(s2h, s2l, s1h, s1l, pc, qc,
                                            W1, b1, W2, b2, w_out);

    topk_kernel<<<(B_ * N_) / 4, 256, 0, stream>>>(w_out, f1, f2, pc, qc,
                                                   W1, b1, W2, b2,
                                                   f_out, idx_out);
}

// Round 2
// 517.853 us; speedup vs baseline: 2.3911x; 1.1871x over previous
//
#include <hip/hip_runtime.h>
#include <math.h>

// Problem constants (fixed by setup_inputs)
constexpr int B_ = 8;
constexpr int N_ = 2048;
constexpr int D_ = 256;
constexpr int H_ = 16;
constexpr int K_ = 8;
constexpr int CAND = 32;   // candidate pool for exact re-ranking

constexpr int BM = 128;    // tile rows (q and p)
constexpr int BK = 64;     // k chunk per stage (2 MFMA K-steps)

typedef __bf16 bf16x8 __attribute__((ext_vector_type(8)));
typedef float  f32x4  __attribute__((ext_vector_type(4)));

// address-space-qualified pointers for global_load_lds
typedef __attribute__((address_space(3))) unsigned int       lds_u32_t;
typedef __attribute__((address_space(1))) const unsigned int glb_u32_t;

__device__ __forceinline__ void g2l16(const void* g, void* l) {
    // 16B direct global->LDS (dest = wave-uniform base + lane*16)
    __builtin_amdgcn_global_load_lds((glb_u32_t*)g, (lds_u32_t*)l, 16, 0, 0);
}

// order-preserving float -> uint map: a > b  <=>  ford(a) > ford(b)
__device__ __forceinline__ unsigned ford(float f) {
    unsigned u = __float_as_uint(f);
    return (u & 0x80000000u) ? ~u : (u | 0x80000000u);
}

// ---------------------------------------------------------------------------
// split fp32*scale -> packed bf16 hi (truncated) + bf16 lo (residual, trunc)
// (identical numerics to the verified kernel)
// ---------------------------------------------------------------------------
__device__ inline void split4(float4 v, float s, uint2& hi, uint2& lo) {
    float a = v.x * s, b = v.y * s, c = v.z * s, d = v.w * s;
    unsigned ua = __float_as_uint(a), ub = __float_as_uint(b);
    unsigned uc = __float_as_uint(c), ud = __float_as_uint(d);
    unsigned ha = ua & 0xFFFF0000u, hb = ub & 0xFFFF0000u;
    unsigned hc = uc & 0xFFFF0000u, hd = ud & 0xFFFF0000u;
    hi.x = (ha >> 16) | hb;
    hi.y = (hc >> 16) | hd;
    float ra = a - __uint_as_float(ha), rb = b - __uint_as_float(hb);
    float rc = c - __uint_as_float(hc), rd = d - __uint_as_float(hd);
    lo.x = (__float_as_uint(ra) >> 16) | (__float_as_uint(rb) & 0xFFFF0000u);
    lo.y = (__float_as_uint(rc) >> 16) | (__float_as_uint(rd) & 0xFFFF0000u);
}

// ---------------------------------------------------------------------------
// Kernel 1 (prep): fp32 -> normalized bf16 hi/lo, stored tile-panel-major and
// PRE-SWIZZLED so that a linear global_load_lds copy yields a bank-conflict-
// free LDS layout (m173 pattern: swizzle the source, keep LDS linear).
// ---------------------------------------------------------------------------
__global__ __launch_bounds__(256)
void prep_kernel(const float* __restrict__ f1, const float* __restrict__ f2,
                 unsigned short* __restrict__ s1h, unsigned short* __restrict__ s1l,
                 unsigned short* __restrict__ s2h, unsigned short* __restrict__ s2l) {
    int gid  = blockIdx.x * blockDim.x + threadIdx.x;
    int wave = gid >> 6;
    int lane = gid & 63;
    if (wave >= 2 * B_ * N_) return;
    bool is1 = wave < B_ * N_;
    int r = is1 ? wave : wave - B_ * N_;

    const float* src = (is1 ? f1 : f2) + (size_t)r * D_;
    float4 v = *(const float4*)(src + lane * 4);
    float ss = v.x * v.x + v.y * v.y + v.z * v.z + v.w * v.w;
#pragma unroll
    for (int off = 32; off > 0; off >>= 1) ss += __shfl_xor(ss, off, 64);
    float inv = 1.0f / (sqrtf(ss) + 1e-8f);

    uint2 hi, lo;
    split4(v, inv, hi, lo);

    int panel = r >> 7, rloc = r & 127;
    int slot  = lane >> 1;                 // 16B slot index 0..31
    int chunk = slot >> 3;                 // which 64-elem k-chunk (tile)
    int sl    = (slot & 7) ^ (rloc & 7);   // swizzled slot within 128B row
    int half  = lane & 1;
    size_t idx = ((size_t)(panel * 4 + chunk) << 13)   // tile * 8192 ushorts
               + (size_t)rloc * 64 + sl * 8 + half * 4;
    *(uint2*)&(is1 ? s1h : s2h)[idx] = hi;
    *(uint2*)&(is1 ? s1l : s2l)[idx] = lo;
}

// ---------------------------------------------------------------------------
// Kernel 2: MFMA cosine-sim GEMM (bf16x3 split precision) + coord dist + MLP.
// (unchanged from round 1 — verified)
// ---------------------------------------------------------------------------
__global__ __launch_bounds__(256, 2)
void gemm_mlp_kernel(const unsigned short* __restrict__ aH0,  // f2 hi (A side, q)
                     const unsigned short* __restrict__ aL0,  // f2 lo
                     const unsigned short* __restrict__ bH0,  // f1 hi (B side, p)
                     const unsigned short* __restrict__ bL0,  // f1 lo
                     const float* __restrict__ pc, const float* __restrict__ qc,
                     const float* __restrict__ pW1, const float* __restrict__ pb1,
                     const float* __restrict__ pW2, const float* __restrict__ pb2,
                     float* __restrict__ w_out) {
    // 4 linear tiles: Ahi | Alo | Bhi | Blo, 16 KiB each = 64 KiB
    __shared__ unsigned short ldsbuf[4 * 8192];

    int tid = threadIdx.x;
    // bijective XCD chunking swizzle within each z-slice (256 blocks, 256%8==0)
    int l  = blockIdx.x + (blockIdx.y << 4);
    int ls = ((l & 7) << 5) | (l >> 3);
    int pBase = (ls & 15) * BM;
    int qBase = (ls >> 4) * BM;
    int b = blockIdx.z;

    int lane = tid & 63;
    int wv   = tid >> 6;
    int wq = (wv >> 1) * 64;
    int wp = (wv & 1) * 64;
    int fr = lane & 15;
    int kg = lane >> 4;

    const int Apanel = ((b * N_ + qBase) >> 7) * 4;
    const int Bpanel = ((b * N_ + pBase) >> 7) * 4;

    char* ldsB = (char*)&ldsbuf[0];
    int soff = (wv << 10) + (lane << 4);   // per-lane global byte offset
    int doff = (wv << 10);                 // wave-uniform LDS byte offset

    f32x4 acc[4][4] = {};

#pragma unroll
    for (int c = 0; c < 4; c++) {          // 4 K-chunks of 64
        __syncthreads();                   // previous compute done reading LDS
        const char* aH = (const char*)aH0 + ((size_t)(Apanel + c) << 14);
        const char* aL = (const char*)aL0 + ((size_t)(Apanel + c) << 14);
        const char* bH = (const char*)bH0 + ((size_t)(Bpanel + c) << 14);
        const char* bL = (const char*)bL0 + ((size_t)(Bpanel + c) << 14);
#pragma unroll
        for (int i = 0; i < 4; i++) {      // 4 issues/wave fill 16 KiB/tile
            int o = (i << 12);
            g2l16(aH + o + soff, ldsB + 0     + o + doff);
            g2l16(aL + o + soff, ldsB + 16384 + o + doff);
            g2l16(bH + o + soff, ldsB + 32768 + o + doff);
            g2l16(bL + o + soff, ldsB + 49152 + o + doff);
        }
        __syncthreads();                   // compiler drains vmcnt before barrier

#pragma unroll
        for (int ks = 0; ks < 2; ks++) {   // two K=32 MFMA steps per chunk
            bf16x8 ah[4], al[4], bh[4], bl[4];
#pragma unroll
            for (int t = 0; t < 4; t++) {
                int ra = (wq + t * 16 + fr) * 128;
                int rb = (wp + t * 16 + fr) * 128;
                int cw = ((ks * 4 + kg) ^ (fr & 7)) << 4;  // swizzled 16B slot
                ah[t] = *(const bf16x8*)(ldsB + 0     + ra + cw);
                al[t] = *(const bf16x8*)(ldsB + 16384 + ra + cw);
                bh[t] = *(const bf16x8*)(ldsB + 32768 + rb + cw);
                bl[t] = *(const bf16x8*)(ldsB + 49152 + rb + cw);
            }
#pragma unroll
            for (int qt = 0; qt < 4; qt++) {
#pragma unroll
                for (int pt = 0; pt < 4; pt++) {
                    acc[qt][pt] = __builtin_amdgcn_mfma_f32_16x16x32_bf16(
                        ah[qt], bh[pt], acc[qt][pt], 0, 0, 0);
                    acc[qt][pt] = __builtin_amdgcn_mfma_f32_16x16x32_bf16(
                        ah[qt], bl[pt], acc[qt][pt], 0, 0, 0);
                    acc[qt][pt] = __builtin_amdgcn_mfma_f32_16x16x32_bf16(
                        al[qt], bh[pt], acc[qt][pt], 0, 0, 0);
                }
            }
        }
    }

    // ---------------- epilogue: coord term + MLP + store -------------------
    float px[4], py[4], pz[4], pn2[4];
    int pg[4];
#pragma unroll
    for (int pt = 0; pt < 4; pt++) {
        int p = pBase + wp + pt * 16 + fr;
        pg[pt] = p;
        const float* pp = pc + ((size_t)(b * N_ + p)) * 3;
        px[pt] = pp[0]; py[pt] = pp[1]; pz[pt] = pp[2];
        pn2[pt] = px[pt] * px[pt] + py[pt] * py[pt] + pz[pt] * pz[pt];
    }
#pragma unroll
    for (int qt = 0; qt < 4; qt++) {
        float qx[4], qy[4], qz[4], qq2[4];
        int q0 = qBase + wq + qt * 16 + kg * 4;
#pragma unroll
        for (int r = 0; r < 4; r++) {
            const float* qp = qc + ((size_t)(b * N_ + q0 + r)) * 3;
            qx[r] = qp[0]; qy[r] = qp[1]; qz[r] = qp[2];
            qq2[r] = qx[r] * qx[r] + qy[r] * qy[r] + qz[r] * qz[r];
        }
#pragma unroll
        for (int pt = 0; pt < 4; pt++) {
            f32x4 cval = acc[qt][pt];
#pragma unroll
            for (int r = 0; r < 4; r++) {
                float w1v = cval[r];
                float d2 = qq2[r] + pn2[pt]
                         - 2.f * (qx[r] * px[pt] + qy[r] * py[pt] + qz[r] * pz[pt]);
                float w2v = -fmaxf(d2, 0.f);
                float out = pb2[0];
#pragma unroll
                for (int h = 0; h < H_; h++) {
                    float t = pW1[2 * h] * w1v + pW1[2 * h + 1] * w2v + pb1[h];
                    out += pW2[h] * fmaxf(t, 0.f);
                }
                w_out[((size_t)(b * N_ + q0 + r)) * N_ + pg[pt]] = out;
            }
        }
    }
}

// ---------------------------------------------------------------------------
// Kernel 3: approx top-32 candidates (ballot threshold select) -> exact fp64
// rescore -> exact top-8 via LDS rank -> softmax + gather + pool.
// One wave per (b,q) row, 4 rows per block.
// ---------------------------------------------------------------------------
__global__ __launch_bounds__(256)
void topk_kernel(const float* __restrict__ w, const float* __restrict__ f1,
                 const float* __restrict__ f2,
                 const float* __restrict__ pc, const float* __restrict__ qc,
                 const float* __restrict__ pW1, const float* __restrict__ pb1,
                 const float* __restrict__ pW2, const float* __restrict__ pb2,
                 float* __restrict__ f_out, float* __restrict__ idx_out) {
    __shared__ int    s_cand[4][CAND];
    __shared__ double s_val[4][CAND];
    __shared__ int    s_idx[4][CAND];
    __shared__ double s_rv[4][K_];
    __shared__ int    s_ri[4][K_];

    int tid  = threadIdx.x;
    int wix  = tid >> 6;
    int lane = tid & 63;
    int row  = blockIdx.x * 4 + wix;          // grid is exact: row < B_*N_
    int b    = row >> 11;
    const float* wrow = w + (size_t)row * N_;

    // ---- phase 1: per-lane sorted top-8 scan of approx scores ----
    float tv[K_];
    int   ti[K_];
#pragma unroll
    for (int s = 0; s < K_; s++) { tv[s] = -INFINITY; ti[s] = 0x7fffffff; }
    for (int j = 0; j < N_ / 256; j++) {
        float4 v4 = *(const float4*)(wrow + lane * 4 + j * 256);
        float vv[4] = {v4.x, v4.y, v4.z, v4.w};
#pragma unroll
        for (int c = 0; c < 4; c++) {
            float v = vv[c];
            if (v > tv[K_ - 1]) {
                int idx = lane * 4 + j * 256 + c;
                tv[K_ - 1] = v; ti[K_ - 1] = idx;
#pragma unroll
                for (int s = K_ - 1; s > 0; s--) {
                    if (tv[s] > tv[s - 1]) {
                        float tf = tv[s]; tv[s] = tv[s - 1]; tv[s - 1] = tf;
                        int tn = ti[s]; ti[s] = ti[s - 1]; ti[s - 1] = tn;
                    }
                }
            }
        }
    }

    // ---- phase 2: wave top-32 of the 512 per-lane values via ballot binary
    // search on order-preserving uint keys (no serial shuffle chain) ----
    unsigned uk[K_];
#pragma unroll
    for (int s = 0; s < K_; s++) uk[s] = ford(tv[s]);

    unsigned T = 0;
    for (int bit = 31; bit >= 0; --bit) {
        unsigned c = T | (1u << bit);
        int cnt = 0;
#pragma unroll
        for (int s = 0; s < K_; s++)
            cnt += __popcll(__ballot(uk[s] >= c));
        if (cnt >= CAND) T = c;   // keep bit: still >= 32 values above
    }
    // T is now the CAND-th largest key; compact indices of values >= T.
    unsigned long long below = (1ull << lane) - 1ull;
    int total = 0;
#pragma unroll
    for (int s = 0; s < K_; s++) {
        unsigned long long m = __ballot(uk[s] >= T);
        int pos = total + __popcll(m & below);
        if (uk[s] >= T && pos < CAND) s_cand[wix][pos] = ti[s];
        total += __popcll(m);
    }
    __syncthreads();

    // ---- phase 3: parallel exact fp64 rescore ----
    int sl = lane & 7;
    int gr = lane >> 3;
    const float* f2r = f2 + (size_t)row * D_ + sl * 32;
    float4 a4[8];
#pragma unroll
    for (int t = 0; t < 8; t++) a4[t] = *(const float4*)(f2r + t * 4);

    double daa = 0.0;
#pragma unroll
    for (int t = 0; t < 8; t++) {
        daa += (double)a4[t].x * (double)a4[t].x;
        daa += (double)a4[t].y * (double)a4[t].y;
        daa += (double)a4[t].z * (double)a4[t].z;
        daa += (double)a4[t].w * (double)a4[t].w;
    }
#pragma unroll
    for (int off = 1; off < 8; off <<= 1) daa += __shfl_xor(daa, off, 64);
    double inv_a = 1.0 / (sqrt(daa) + 1e-8);

    double mydab = 0.0, mydbb = 0.0;
    int myci = 0x7fffffff;
#pragma unroll
    for (int r = 0; r < 4; r++) {
        int cj = s_cand[wix][8 * r + gr];
        const float* f1r = f1 + ((size_t)(b * N_ + cj)) * D_ + sl * 32;
        double sA = 0.0, sB = 0.0;
#pragma unroll
        for (int t = 0; t < 8; t++) {
            float4 b4 = *(const float4*)(f1r + t * 4);
            double b0 = b4.x, b1 = b4.y, b2 = b4.z, b3 = b4.w;
            sA += (double)a4[t].x * b0; sB += b0 * b0;
            sA += (double)a4[t].y * b1; sB += b1 * b1;
            sA += (double)a4[t].z * b2; sB += b2 * b2;
            sA += (double)a4[t].w * b3; sB += b3 * b3;
        }
#pragma unroll
        for (int off = 1; off < 8; off <<= 1) {
            sA += __shfl_xor(sA, off, 64);
            sB += __shfl_xor(sB, off, 64);
        }
        if (sl == r) { mydab = sA; mydbb = sB; myci = cj; }
    }

    double ex = -INFINITY;
    int    ei = 0x7fffffff;
    if (sl < 4) {
        ei = myci;
        double w1d = mydab * inv_a * (1.0 / (sqrt(mydbb) + 1e-8));
        const float* qp = qc + (size_t)row * 3;
        double qx = qp[0], qy = qp[1], qz = qp[2];
        const float* pp = pc + ((size_t)(b * N_ + myci)) * 3;
        double px = pp[0], py = pp[1], pz = pp[2];
        double d2 = (qx * qx + qy * qy + qz * qz) + (px * px + py * py + pz * pz)
                  - 2.0 * (qx * px + qy * py + qz * pz);
        double w2d = -fmax(d2, 0.0);
        double out = (double)pb2[0];
#pragma unroll
        for (int h = 0; h < H_; h++) {
            double t = (double)pW1[2 * h] * w1d + (double)pW1[2 * h + 1] * w2d
                     + (double)pb1[h];
            out += (double)pW2[h] * fmax(t, 0.0);
        }
        ex = out;
    }

    // ---- phase 4: exact top-8 via LDS rank (desc, smaller idx tie) ----
    // 32 scorer lanes (sl<4) write (score,idx); each computes its exact rank
    // with broadcast LDS reads; ranks 0..7 scatter into sorted slots.
    int slot = gr * 4 + sl;                  // 0..31 for scorer lanes
    if (sl < 4) {
        s_val[wix][slot] = ex;
        s_idx[wix][slot] = ei;
    }
    asm volatile("s_waitcnt lgkmcnt(0)" ::: "memory");   // in-wave LDS drain
    if (sl < 4) {
        int rank = 0;
#pragma unroll
        for (int j = 0; j < CAND; j++) {
            double vj = s_val[wix][j];
            int    ij = s_idx[wix][j];
            rank += (vj > ex || (vj == ex && ij < ei)) ? 1 : 0;
        }
        if (rank < K_) { s_rv[wix][rank] = ex; s_ri[wix][rank] = ei; }
    }
    asm volatile("s_waitcnt lgkmcnt(0)" ::: "memory");   // in-wave LDS drain

    double outv[K_];
    int    outi[K_];
#pragma unroll
    for (int r = 0; r < K_; r++) { outv[r] = s_rv[wix][r]; outi[r] = s_ri[wix][r]; }

    // ---- phase 5: softmax + gather + pool + write ----
    float m = (float)outv[0];
    float e[K_], s = 0.f;
#pragma unroll
    for (int r = 0; r < K_; r++) { e[r] = expf((float)outv[r] - m); s += e[r]; }
    float inv_s = 1.f / s;

    const float* f1b = f1 + ((size_t)b * N_) * D_;
    size_t obase = (size_t)row * (2 * D_);
#pragma unroll
    for (int jd = 0; jd < D_ / 64; jd++) {
        int d = lane + 64 * jd;
        float accv = 0.f, mx = -INFINITY;
#pragma unroll
        for (int r = 0; r < K_; r++) {
            float x = f1b[(size_t)outi[r] * D_ + d];
            accv += (e[r] * inv_s) * x;
            mx = fmaxf(mx, x);
        }
        f_out[obase + d]      = accv;
        f_out[obase + D_ + d] = mx;
    }
    if (lane == 0) {
#pragma unroll
        for (int r = 0; r < K_; r++) idx_out[(size_t)row * K_ + r] = (float)outi[r];
    }
}

// ---------------------------------------------------------------------------
extern "C" void kernel_launch(void* const* d_in, const int* in_sizes, int n_in,
                              void* d_out, int out_size, void* d_ws, size_t ws_size,
                              hipStream_t stream) {
    const float* f1 = (const float*)d_in[0];
    const float* f2 = (const float*)d_in[1];
    const float* pc = (const float*)d_in[2];
    const float* qc = (const float*)d_in[3];
    const float* W1 = (const float*)d_in[4];
    const float* b1 = (const float*)d_in[5];
    const float* W2 = (const float*)d_in[6];
    const float* b2 = (const float*)d_in[7];

    float* out     = (float*)d_out;
    float* f_out   = out;                                   // [B,N,2D]
    float* idx_out = f_out + (size_t)B_ * N_ * 2 * D_;      // [B,N,K] as float
    float* w_out   = idx_out + (size_t)B_ * N_ * K_;        // [B,N,N]

    // Scratch bf16 hi/lo panels live in the f_out region (33,554,432 B,
    // exactly 4 arrays of B*N*D ushorts). f_out is only written by
    // topk_kernel afterwards, so this is safe under stream ordering.
    unsigned short* s1h = (unsigned short*)f_out;           // f1 hi (B side)
    unsigned short* s1l = s1h + (size_t)B_ * N_ * D_;       // f1 lo
    unsigned short* s2h = s1l + (size_t)B_ * N_ * D_;       // f2 hi (A side)
    unsigned short* s2l = s2h + (size_t)B_ * N_ * D_;       // f2 lo

    prep_kernel<<<(2 * B_ * N_) / 4, 256, 0, stream>>>(f1, f2, s1h, s1l, s2h, s2l);

    dim3 g2(N_ / BM, N_ / BM, B_);
    gemm_mlp_kernel<<<g2, 256, 0, stream>>>(s2h, s2l, s1h, s1l, pc, qc,
                                            W1, b1, W2, b2, w_out);

    topk_kernel<<<(B_ * N_) / 4, 256, 0, stream>>>(w_out, f1, f2, pc, qc,
                                                   W1, b1, W2, b2,
                                                   f_out, idx_out);
}

// Round 3
// 484.514 us; speedup vs baseline: 2.5556x; 1.0688x over previous
//
#include <hip/hip_runtime.h>
#include <math.h>

// Problem constants (fixed by setup_inputs)
constexpr int B_ = 8;
constexpr int N_ = 2048;
constexpr int D_ = 256;
constexpr int H_ = 16;
constexpr int K_ = 8;
constexpr int CAND = 32;   // candidate pool for exact re-ranking

constexpr int BM = 128;    // tile rows (q and p)
constexpr int BK = 64;     // k chunk per stage (2 MFMA K-steps)

typedef _Float16 f16x8 __attribute__((ext_vector_type(8)));
typedef float    f32x4 __attribute__((ext_vector_type(4)));

// address-space-qualified pointers for global_load_lds
typedef __attribute__((address_space(3))) unsigned int       lds_u32_t;
typedef __attribute__((address_space(1))) const unsigned int glb_u32_t;

__device__ __forceinline__ void g2l16(const void* g, void* l) {
    // 16B direct global->LDS (dest = wave-uniform base + lane*16)
    __builtin_amdgcn_global_load_lds((glb_u32_t*)g, (lds_u32_t*)l, 16, 0, 0);
}

// order-preserving float -> uint map: a > b  <=>  ford(a) > ford(b)
__device__ __forceinline__ unsigned ford(float f) {
    unsigned u = __float_as_uint(f);
    return (u & 0x80000000u) ? ~u : (u | 0x80000000u);
}

__device__ __forceinline__ unsigned pk16(_Float16 a, _Float16 b) {
    unsigned short ua = __builtin_bit_cast(unsigned short, a);
    unsigned short ub = __builtin_bit_cast(unsigned short, b);
    return (unsigned)ua | ((unsigned)ub << 16);
}

// fp32*scale -> fp16 hi (RNE) + fp16 lo (RNE residual), packed pairs
__device__ inline void split4_f16(float4 v, float s, uint2& hi, uint2& lo) {
    float a = v.x * s, b = v.y * s, c = v.z * s, d = v.w * s;
    _Float16 ha = (_Float16)a, hb = (_Float16)b;
    _Float16 hc = (_Float16)c, hd = (_Float16)d;
    _Float16 la = (_Float16)(a - (float)ha), lb = (_Float16)(b - (float)hb);
    _Float16 lc = (_Float16)(c - (float)hc), ld = (_Float16)(d - (float)hd);
    hi.x = pk16(ha, hb); hi.y = pk16(hc, hd);
    lo.x = pk16(la, lb); lo.y = pk16(lc, ld);
}

// ---------------------------------------------------------------------------
// Kernel 1 (prep): fp32 -> normalized fp16 split, stored tile-panel-major and
// PRE-SWIZZLED so that a linear global_load_lds copy yields a bank-conflict-
// free LDS layout.  f1 (B side): hi + lo.  f2 (A side): hi only.
// Tile = [128 rows][64 k-elems] fp16 = 16 KiB; tile idx = (row/128)*4+(k/64).
// Within a row (128 B, 8 slots of 16 B): slot' = slot ^ (row & 7).
// ---------------------------------------------------------------------------
__global__ __launch_bounds__(256)
void prep_kernel(const float* __restrict__ f1, const float* __restrict__ f2,
                 unsigned short* __restrict__ s1h, unsigned short* __restrict__ s1l,
                 unsigned short* __restrict__ s2h) {
    int gid  = blockIdx.x * blockDim.x + threadIdx.x;
    int wave = gid >> 6;
    int lane = gid & 63;
    if (wave >= 2 * B_ * N_) return;
    bool is1 = wave < B_ * N_;
    int r = is1 ? wave : wave - B_ * N_;

    const float* src = (is1 ? f1 : f2) + (size_t)r * D_;
    float4 v = *(const float4*)(src + lane * 4);
    float ss = v.x * v.x + v.y * v.y + v.z * v.z + v.w * v.w;
#pragma unroll
    for (int off = 32; off > 0; off >>= 1) ss += __shfl_xor(ss, off, 64);
    float inv = 1.0f / (sqrtf(ss) + 1e-8f);

    uint2 hi, lo;
    split4_f16(v, inv, hi, lo);

    int panel = r >> 7, rloc = r & 127;
    int slot  = lane >> 1;                 // 16B slot index 0..31 (across 256 el)
    int chunk = slot >> 3;                 // which 64-elem k-chunk (tile)
    int sl    = (slot & 7) ^ (rloc & 7);   // swizzled slot within 128B row
    int half  = lane & 1;
    size_t idx = ((size_t)(panel * 4 + chunk) << 13)   // tile * 8192 ushorts
               + (size_t)rloc * 64 + sl * 8 + half * 4;
    if (is1) {
        *(uint2*)&s1h[idx] = hi;
        *(uint2*)&s1l[idx] = lo;
    } else {
        *(uint2*)&s2h[idx] = hi;
    }
}

// ---------------------------------------------------------------------------
// Kernel 2: MFMA cosine-sim GEMM (asymmetric fp16 2-term: hA*(hB+lB)) +
// coord dist + MLP.  48 KiB LDS -> 3 blocks/CU.  Same verified structure,
// layout, and addressing as round 2; one MFMA product removed.
// ---------------------------------------------------------------------------
__global__ __launch_bounds__(256, 3)
void gemm_mlp_kernel(const unsigned short* __restrict__ aH0,  // f2 hi (A, q)
                     const unsigned short* __restrict__ bH0,  // f1 hi (B, p)
                     const unsigned short* __restrict__ bL0,  // f1 lo (B, p)
                     const float* __restrict__ pc, const float* __restrict__ qc,
                     const float* __restrict__ pW1, const float* __restrict__ pb1,
                     const float* __restrict__ pW2, const float* __restrict__ pb2,
                     float* __restrict__ w_out) {
    // 3 linear tiles: Ahi | Bhi | Blo, 16 KiB each = 48 KiB
    __shared__ unsigned short ldsbuf[3 * 8192];

    int tid = threadIdx.x;
    // bijective XCD chunking swizzle within each z-slice (256 blocks, 256%8==0)
    int l  = blockIdx.x + (blockIdx.y << 4);
    int ls = ((l & 7) << 5) | (l >> 3);
    int pBase = (ls & 15) * BM;
    int qBase = (ls >> 4) * BM;
    int b = blockIdx.z;

    int lane = tid & 63;
    int wv   = tid >> 6;
    int wq = (wv >> 1) * 64;
    int wp = (wv & 1) * 64;
    int fr = lane & 15;
    int kg = lane >> 4;

    const int Apanel = ((b * N_ + qBase) >> 7) * 4;
    const int Bpanel = ((b * N_ + pBase) >> 7) * 4;

    char* ldsB = (char*)&ldsbuf[0];
    int soff = (wv << 10) + (lane << 4);   // per-lane global byte offset
    int doff = (wv << 10);                 // wave-uniform LDS byte offset

    f32x4 acc[4][4] = {};

#pragma unroll
    for (int c = 0; c < 4; c++) {          // 4 K-chunks of 64
        __syncthreads();                   // previous compute done reading LDS
        const char* aH = (const char*)aH0 + ((size_t)(Apanel + c) << 14);
        const char* bH = (const char*)bH0 + ((size_t)(Bpanel + c) << 14);
        const char* bL = (const char*)bL0 + ((size_t)(Bpanel + c) << 14);
#pragma unroll
        for (int i = 0; i < 4; i++) {      // 4 issues/wave fill 16 KiB/tile
            int o = (i << 12);
            g2l16(aH + o + soff, ldsB + 0     + o + doff);
            g2l16(bH + o + soff, ldsB + 16384 + o + doff);
            g2l16(bL + o + soff, ldsB + 32768 + o + doff);
        }
        __syncthreads();                   // compiler drains vmcnt before barrier

#pragma unroll
        for (int ks = 0; ks < 2; ks++) {   // two K=32 MFMA steps per chunk
            f16x8 ah[4], bh[4], bl[4];
#pragma unroll
            for (int t = 0; t < 4; t++) {
                int ra = (wq + t * 16 + fr) * 128;
                int rb = (wp + t * 16 + fr) * 128;
                int cw = ((ks * 4 + kg) ^ (fr & 7)) << 4;  // swizzled 16B slot
                ah[t] = *(const f16x8*)(ldsB + 0     + ra + cw);
                bh[t] = *(const f16x8*)(ldsB + 16384 + rb + cw);
                bl[t] = *(const f16x8*)(ldsB + 32768 + rb + cw);
            }
#pragma unroll
            for (int qt = 0; qt < 4; qt++) {
#pragma unroll
                for (int pt = 0; pt < 4; pt++) {
                    acc[qt][pt] = __builtin_amdgcn_mfma_f32_16x16x32_f16(
                        ah[qt], bh[pt], acc[qt][pt], 0, 0, 0);
                    acc[qt][pt] = __builtin_amdgcn_mfma_f32_16x16x32_f16(
                        ah[qt], bl[pt], acc[qt][pt], 0, 0, 0);
                }
            }
        }
    }

    // ---------------- epilogue: coord term + MLP + store -------------------
    float px[4], py[4], pz[4], pn2[4];
    int pg[4];
#pragma unroll
    for (int pt = 0; pt < 4; pt++) {
        int p = pBase + wp + pt * 16 + fr;
        pg[pt] = p;
        const float* pp = pc + ((size_t)(b * N_ + p)) * 3;
        px[pt] = pp[0]; py[pt] = pp[1]; pz[pt] = pp[2];
        pn2[pt] = px[pt] * px[pt] + py[pt] * py[pt] + pz[pt] * pz[pt];
    }
#pragma unroll
    for (int qt = 0; qt < 4; qt++) {
        float qx[4], qy[4], qz[4], qq2[4];
        int q0 = qBase + wq + qt * 16 + kg * 4;
#pragma unroll
        for (int r = 0; r < 4; r++) {
            const float* qp = qc + ((size_t)(b * N_ + q0 + r)) * 3;
            qx[r] = qp[0]; qy[r] = qp[1]; qz[r] = qp[2];
            qq2[r] = qx[r] * qx[r] + qy[r] * qy[r] + qz[r] * qz[r];
        }
#pragma unroll
        for (int pt = 0; pt < 4; pt++) {
            f32x4 cval = acc[qt][pt];
#pragma unroll
            for (int r = 0; r < 4; r++) {
                float w1v = cval[r];
                float d2 = qq2[r] + pn2[pt]
                         - 2.f * (qx[r] * px[pt] + qy[r] * py[pt] + qz[r] * pz[pt]);
                float w2v = -fmaxf(d2, 0.f);
                float out = pb2[0];
#pragma unroll
                for (int h = 0; h < H_; h++) {
                    float t = pW1[2 * h] * w1v + pW1[2 * h + 1] * w2v + pb1[h];
                    out += pW2[h] * fmaxf(t, 0.f);
                }
                w_out[((size_t)(b * N_ + q0 + r)) * N_ + pg[pt]] = out;
            }
        }
    }
}

// ---------------------------------------------------------------------------
// Kernel 3: approx top-32 candidates (ballot threshold select) -> exact fp64
// rescore -> exact top-8 via LDS rank -> softmax + gather + pool.
// One wave per (b,q) row, 4 rows per block.  (unchanged from round 2)
// ---------------------------------------------------------------------------
__global__ __launch_bounds__(256)
void topk_kernel(const float* __restrict__ w, const float* __restrict__ f1,
                 const float* __restrict__ f2,
                 const float* __restrict__ pc, const float* __restrict__ qc,
                 const float* __restrict__ pW1, const float* __restrict__ pb1,
                 const float* __restrict__ pW2, const float* __restrict__ pb2,
                 float* __restrict__ f_out, float* __restrict__ idx_out) {
    __shared__ int    s_cand[4][CAND];
    __shared__ double s_val[4][CAND];
    __shared__ int    s_idx[4][CAND];
    __shared__ double s_rv[4][K_];
    __shared__ int    s_ri[4][K_];

    int tid  = threadIdx.x;
    int wix  = tid >> 6;
    int lane = tid & 63;
    int row  = blockIdx.x * 4 + wix;          // grid is exact: row < B_*N_
    int b    = row >> 11;
    const float* wrow = w + (size_t)row * N_;

    // ---- phase 1: per-lane sorted top-8 scan of approx scores ----
    float tv[K_];
    int   ti[K_];
#pragma unroll
    for (int s = 0; s < K_; s++) { tv[s] = -INFINITY; ti[s] = 0x7fffffff; }
    for (int j = 0; j < N_ / 256; j++) {
        float4 v4 = *(const float4*)(wrow + lane * 4 + j * 256);
        float vv[4] = {v4.x, v4.y, v4.z, v4.w};
#pragma unroll
        for (int c = 0; c < 4; c++) {
            float v = vv[c];
            if (v > tv[K_ - 1]) {
                int idx = lane * 4 + j * 256 + c;
                tv[K_ - 1] = v; ti[K_ - 1] = idx;
#pragma unroll
                for (int s = K_ - 1; s > 0; s--) {
                    if (tv[s] > tv[s - 1]) {
                        float tf = tv[s]; tv[s] = tv[s - 1]; tv[s - 1] = tf;
                        int tn = ti[s]; ti[s] = ti[s - 1]; ti[s - 1] = tn;
                    }
                }
            }
        }
    }

    // ---- phase 2: wave top-32 via ballot binary search on uint keys ----
    unsigned uk[K_];
#pragma unroll
    for (int s = 0; s < K_; s++) uk[s] = ford(tv[s]);

    unsigned T = 0;
    for (int bit = 31; bit >= 0; --bit) {
        unsigned c = T | (1u << bit);
        int cnt = 0;
#pragma unroll
        for (int s = 0; s < K_; s++)
            cnt += __popcll(__ballot(uk[s] >= c));
        if (cnt >= CAND) T = c;   // keep bit: still >= 32 values above
    }
    // T is now the CAND-th largest key; compact indices of values >= T.
    unsigned long long below = (1ull << lane) - 1ull;
    int total = 0;
#pragma unroll
    for (int s = 0; s < K_; s++) {
        unsigned long long m = __ballot(uk[s] >= T);
        int pos = total + __popcll(m & below);
        if (uk[s] >= T && pos < CAND) s_cand[wix][pos] = ti[s];
        total += __popcll(m);
    }
    __syncthreads();

    // ---- phase 3: parallel exact fp64 rescore ----
    int sl = lane & 7;
    int gr = lane >> 3;
    const float* f2r = f2 + (size_t)row * D_ + sl * 32;
    float4 a4[8];
#pragma unroll
    for (int t = 0; t < 8; t++) a4[t] = *(const float4*)(f2r + t * 4);

    double daa = 0.0;
#pragma unroll
    for (int t = 0; t < 8; t++) {
        daa += (double)a4[t].x * (double)a4[t].x;
        daa += (double)a4[t].y * (double)a4[t].y;
        daa += (double)a4[t].z * (double)a4[t].z;
        daa += (double)a4[t].w * (double)a4[t].w;
    }
#pragma unroll
    for (int off = 1; off < 8; off <<= 1) daa += __shfl_xor(daa, off, 64);
    double inv_a = 1.0 / (sqrt(daa) + 1e-8);

    double mydab = 0.0, mydbb = 0.0;
    int myci = 0x7fffffff;
#pragma unroll
    for (int r = 0; r < 4; r++) {
        int cj = s_cand[wix][8 * r + gr];
        const float* f1r = f1 + ((size_t)(b * N_ + cj)) * D_ + sl * 32;
        double sA = 0.0, sB = 0.0;
#pragma unroll
        for (int t = 0; t < 8; t++) {
            float4 b4 = *(const float4*)(f1r + t * 4);
            double b0 = b4.x, b1 = b4.y, b2 = b4.z, b3 = b4.w;
            sA += (double)a4[t].x * b0; sB += b0 * b0;
            sA += (double)a4[t].y * b1; sB += b1 * b1;
            sA += (double)a4[t].z * b2; sB += b2 * b2;
            sA += (double)a4[t].w * b3; sB += b3 * b3;
        }
#pragma unroll
        for (int off = 1; off < 8; off <<= 1) {
            sA += __shfl_xor(sA, off, 64);
            sB += __shfl_xor(sB, off, 64);
        }
        if (sl == r) { mydab = sA; mydbb = sB; myci = cj; }
    }

    double ex = -INFINITY;
    int    ei = 0x7fffffff;
    if (sl < 4) {
        ei = myci;
        double w1d = mydab * inv_a * (1.0 / (sqrt(mydbb) + 1e-8));
        const float* qp = qc + (size_t)row * 3;
        double qx = qp[0], qy = qp[1], qz = qp[2];
        const float* pp = pc + ((size_t)(b * N_ + myci)) * 3;
        double px = pp[0], py = pp[1], pz = pp[2];
        double d2 = (qx * qx + qy * qy + qz * qz) + (px * px + py * py + pz * pz)
                  - 2.0 * (qx * px + qy * py + qz * pz);
        double w2d = -fmax(d2, 0.0);
        double out = (double)pb2[0];
#pragma unroll
        for (int h = 0; h < H_; h++) {
            double t = (double)pW1[2 * h] * w1d + (double)pW1[2 * h + 1] * w2d
                     + (double)pb1[h];
            out += (double)pW2[h] * fmax(t, 0.0);
        }
        ex = out;
    }

    // ---- phase 4: exact top-8 via LDS rank (desc, smaller idx tie) ----
    int slot = gr * 4 + sl;                  // 0..31 for scorer lanes
    if (sl < 4) {
        s_val[wix][slot] = ex;
        s_idx[wix][slot] = ei;
    }
    asm volatile("s_waitcnt lgkmcnt(0)" ::: "memory");   // in-wave LDS drain
    if (sl < 4) {
        int rank = 0;
#pragma unroll
        for (int j = 0; j < CAND; j++) {
            double vj = s_val[wix][j];
            int    ij = s_idx[wix][j];
            rank += (vj > ex || (vj == ex && ij < ei)) ? 1 : 0;
        }
        if (rank < K_) { s_rv[wix][rank] = ex; s_ri[wix][rank] = ei; }
    }
    asm volatile("s_waitcnt lgkmcnt(0)" ::: "memory");   // in-wave LDS drain

    double outv[K_];
    int    outi[K_];
#pragma unroll
    for (int r = 0; r < K_; r++) { outv[r] = s_rv[wix][r]; outi[r] = s_ri[wix][r]; }

    // ---- phase 5: softmax + gather + pool + write ----
    float m = (float)outv[0];
    float e[K_], s = 0.f;
#pragma unroll
    for (int r = 0; r < K_; r++) { e[r] = expf((float)outv[r] - m); s += e[r]; }
    float inv_s = 1.f / s;

    const float* f1b = f1 + ((size_t)b * N_) * D_;
    size_t obase = (size_t)row * (2 * D_);
#pragma unroll
    for (int jd = 0; jd < D_ / 64; jd++) {
        int d = lane + 64 * jd;
        float accv = 0.f, mx = -INFINITY;
#pragma unroll
        for (int r = 0; r < K_; r++) {
            float x = f1b[(size_t)outi[r] * D_ + d];
            accv += (e[r] * inv_s) * x;
            mx = fmaxf(mx, x);
        }
        f_out[obase + d]      = accv;
        f_out[obase + D_ + d] = mx;
    }
    if (lane == 0) {
#pragma unroll
        for (int r = 0; r < K_; r++) idx_out[(size_t)row * K_ + r] = (float)outi[r];
    }
}

// ---------------------------------------------------------------------------
extern "C" void kernel_launch(void* const* d_in, const int* in_sizes, int n_in,
                              void* d_out, int out_size, void* d_ws, size_t ws_size,
                              hipStream_t stream) {
    const float* f1 = (const float*)d_in[0];
    const float* f2 = (const float*)d_in[1];
    const float* pc = (const float*)d_in[2];
    const float* qc = (const float*)d_in[3];
    const float* W1 = (const float*)d_in[4];
    const float* b1 = (const float*)d_in[5];
    const float* W2 = (const float*)d_in[6];
    const float* b2 = (const float*)d_in[7];

    float* out     = (float*)d_out;
    float* f_out   = out;                                   // [B,N,2D]
    float* idx_out = f_out + (size_t)B_ * N_ * 2 * D_;      // [B,N,K] as float
    float* w_out   = idx_out + (size_t)B_ * N_ * K_;        // [B,N,N]

    // Scratch fp16 panels live in the f_out region (33,554,432 B >= 3 arrays
    // of B*N*D ushorts = 25.2 MB).  f_out is only written by topk_kernel
    // afterwards, so this is safe under stream ordering.
    unsigned short* s1h = (unsigned short*)f_out;           // f1 hi (B side)
    unsigned short* s1l = s1h + (size_t)B_ * N_ * D_;       // f1 lo (B side)
    unsigned short* s2h = s1l + (size_t)B_ * N_ * D_;       // f2 hi (A side)

    prep_kernel<<<(2 * B_ * N_) / 4, 256, 0, stream>>>(f1, f2, s1h, s1l, s2h);

    dim3 g2(N_ / BM, N_ / BM, B_);
    gemm_mlp_kernel<<<g2, 256, 0, stream>>>(s2h, s1h, s1l, pc, qc,
                                            W1, b1, W2, b2, w_out);

    topk_kernel<<<(B_ * N_) / 4, 256, 0, stream>>>(w_out, f1, f2, pc, qc,
                                                   W1, b1, W2, b2,
                                                   f_out, idx_out);
}

// Round 4
// 414.480 us; speedup vs baseline: 2.9874x; 1.1690x over previous
//
#include <hip/hip_runtime.h>
#include <math.h>

// Problem constants (fixed by setup_inputs)
constexpr int B_ = 8;
constexpr int N_ = 2048;
constexpr int D_ = 256;
constexpr int H_ = 16;
constexpr int K_ = 8;
constexpr int CAND = 32;   // candidate pool for exact re-ranking

constexpr int BM = 128;    // tile rows (q and p)
constexpr int BK = 32;     // k chunk per stage (1 MFMA K-step), double-buffered

typedef _Float16 f16x8 __attribute__((ext_vector_type(8)));
typedef float    f32x4 __attribute__((ext_vector_type(4)));
typedef float    f32x2 __attribute__((ext_vector_type(2)));

// address-space-qualified pointers for global_load_lds
typedef __attribute__((address_space(3))) unsigned int       lds_u32_t;
typedef __attribute__((address_space(1))) const unsigned int glb_u32_t;

__device__ __forceinline__ void g2l16(const void* g, void* l) {
    // 16B direct global->LDS (dest = wave-uniform base + lane*16)
    __builtin_amdgcn_global_load_lds((glb_u32_t*)g, (lds_u32_t*)l, 16, 0, 0);
}

// order-preserving float -> uint map: a > b  <=>  ford(a) > ford(b)
__device__ __forceinline__ unsigned ford(float f) {
    unsigned u = __float_as_uint(f);
    return (u & 0x80000000u) ? ~u : (u | 0x80000000u);
}

__device__ __forceinline__ unsigned pk16(_Float16 a, _Float16 b) {
    unsigned short ua = __builtin_bit_cast(unsigned short, a);
    unsigned short ub = __builtin_bit_cast(unsigned short, b);
    return (unsigned)ua | ((unsigned)ub << 16);
}

// fp32*scale -> fp16 hi (RNE) + fp16 lo (RNE residual), packed pairs
__device__ inline void split4_f16(float4 v, float s, uint2& hi, uint2& lo) {
    float a = v.x * s, b = v.y * s, c = v.z * s, d = v.w * s;
    _Float16 ha = (_Float16)a, hb = (_Float16)b;
    _Float16 hc = (_Float16)c, hd = (_Float16)d;
    _Float16 la = (_Float16)(a - (float)ha), lb = (_Float16)(b - (float)hb);
    _Float16 lc = (_Float16)(c - (float)hc), ld = (_Float16)(d - (float)hd);
    hi.x = pk16(ha, hb); hi.y = pk16(hc, hd);
    lo.x = pk16(la, lb); lo.y = pk16(lc, ld);
}

// ---------------------------------------------------------------------------
// Kernel 1 (prep): fp32 -> normalized fp16 split, stored tile-panel-major and
// PRE-SWIZZLED so a linear global_load_lds copy yields a bank-floor LDS
// layout.  f1 (B side): hi + lo.  f2 (A side): hi only.
// Tile = [128 rows][32 k-elems] fp16 = 8 KiB; tile idx = (row/128)*8+(k/32).
// Within a row (64 B, 4 slots of 16 B): slot' = slot ^ ((row>>1) & 3).
// (slot ^ (row&1-based) would leave ds_read_b128 2x off the bank floor;
//  using row bit1..2 gives 8 distinct (parity,slot) quads x 8 lanes = floor.)
// ---------------------------------------------------------------------------
__global__ __launch_bounds__(256)
void prep_kernel(const float* __restrict__ f1, const float* __restrict__ f2,
                 unsigned short* __restrict__ s1h, unsigned short* __restrict__ s1l,
                 unsigned short* __restrict__ s2h) {
    int gid  = blockIdx.x * blockDim.x + threadIdx.x;
    int wave = gid >> 6;
    int lane = gid & 63;
    if (wave >= 2 * B_ * N_) return;
    bool is1 = wave < B_ * N_;
    int r = is1 ? wave : wave - B_ * N_;

    const float* src = (is1 ? f1 : f2) + (size_t)r * D_;
    float4 v = *(const float4*)(src + lane * 4);
    float ss = v.x * v.x + v.y * v.y + v.z * v.z + v.w * v.w;
#pragma unroll
    for (int off = 32; off > 0; off >>= 1) ss += __shfl_xor(ss, off, 64);
    float inv = 1.0f / (sqrtf(ss) + 1e-8f);

    uint2 hi, lo;
    split4_f16(v, inv, hi, lo);

    int panel = r >> 7, rloc = r & 127;
    int s     = lane >> 1;                   // 16B slot index 0..31 (256 elems)
    int chunk = s >> 2;                      // which 32-elem k-chunk (tile) 0..7
    int sl    = (s & 3) ^ ((rloc >> 1) & 3); // swizzled slot within 64B row
    int half  = lane & 1;
    size_t idx = ((size_t)(panel * 8 + chunk) << 12)   // tile * 4096 ushorts
               + (size_t)rloc * 32 + sl * 8 + half * 4;
    if (is1) {
        *(uint2*)&s1h[idx] = hi;
        *(uint2*)&s1l[idx] = lo;
    } else {
        *(uint2*)&s2h[idx] = hi;
    }
}

// ---------------------------------------------------------------------------
// Kernel 2: MFMA cosine-sim GEMM (asymmetric fp16 2-term: hA*(hB+lB)) +
// coord dist + MLP.  BK=32 double-buffered (2x24 KiB = 48 KiB, 3 blocks/CU)
// with 2-phase prefetch: issue next chunk's global_load_lds BEFORE current
// chunk's ds_read+MFMA; one vmcnt-drain barrier per chunk (T3-minimum).
// Epilogue MLP paired on float2 -> v_pk_fma_f32.
// ---------------------------------------------------------------------------
__global__ __launch_bounds__(256, 3)
void gemm_mlp_kernel(const unsigned short* __restrict__ aH0,  // f2 hi (A, q)
                     const unsigned short* __restrict__ bH0,  // f1 hi (B, p)
                     const unsigned short* __restrict__ bL0,  // f1 lo (B, p)
                     const float* __restrict__ pc, const float* __restrict__ qc,
                     const float* __restrict__ pW1, const float* __restrict__ pb1,
                     const float* __restrict__ pW2, const float* __restrict__ pb2,
                     float* __restrict__ w_out) {
    // 2 buffers x 3 tiles (Ahi | Bhi | Blo) x 8 KiB = 48 KiB
    __shared__ unsigned short ldsbuf[2 * 3 * 4096];

    int tid = threadIdx.x;
    // bijective XCD chunking swizzle within each z-slice (256 blocks, 256%8==0)
    int l  = blockIdx.x + (blockIdx.y << 4);
    int ls = ((l & 7) << 5) | (l >> 3);
    int pBase = (ls & 15) * BM;
    int qBase = (ls >> 4) * BM;
    int b = blockIdx.z;

    int lane = tid & 63;
    int wv   = tid >> 6;
    int wq = (wv >> 1) * 64;
    int wp = (wv & 1) * 64;
    int fr = lane & 15;
    int kg = lane >> 4;

    const int Apanel8 = ((b * N_ + qBase) >> 7) * 8;   // tile idx base (8 KiB tiles)
    const int Bpanel8 = ((b * N_ + pBase) >> 7) * 8;

    char* ldsB = (char*)&ldsbuf[0];
    const int wlo = (wv << 11) + (lane << 4);   // per-lane global byte offset
    const int wdo = (wv << 11);                 // wave-uniform LDS byte offset
    const int cw  = (kg ^ ((fr >> 1) & 3)) << 4;  // swizzled 16B slot (row-bit 1,2)

    f32x4 acc[4][4] = {};

    // STAGE(buf, c): copy chunk c's three 8-KiB tiles into buffer buf
#define STAGE(buf, c)                                                          \
    {                                                                          \
        const char* aH = (const char*)aH0 + ((size_t)(Apanel8 + (c)) << 13);   \
        const char* bH = (const char*)bH0 + ((size_t)(Bpanel8 + (c)) << 13);   \
        const char* bL = (const char*)bL0 + ((size_t)(Bpanel8 + (c)) << 13);   \
        char* dst = ldsB + (buf) * 24576;                                      \
        _Pragma("unroll")                                                      \
        for (int i = 0; i < 2; i++) {                                          \
            int o = i << 10;                                                   \
            g2l16(aH + wlo + o, dst + 0     + wdo + o);                        \
            g2l16(bH + wlo + o, dst + 8192  + wdo + o);                        \
            g2l16(bL + wlo + o, dst + 16384 + wdo + o);                        \
        }                                                                      \
    }

    STAGE(0, 0);
    __syncthreads();                       // drain: buf0 ready

#pragma unroll
    for (int c = 0; c < 8; c++) {          // 8 K-chunks of 32
        if (c < 7) STAGE((c + 1) & 1, c + 1);   // prefetch next (other buffer)

        char* base = ldsB + (c & 1) * 24576;
        f16x8 ah[4], bh[4], bl[4];
#pragma unroll
        for (int t = 0; t < 4; t++) {
            int ra = (wq + t * 16 + fr) * 64;
            int rb = (wp + t * 16 + fr) * 64;
            ah[t] = *(const f16x8*)(base + 0     + ra + cw);
            bh[t] = *(const f16x8*)(base + 8192  + rb + cw);
            bl[t] = *(const f16x8*)(base + 16384 + rb + cw);
        }
#pragma unroll
        for (int qt = 0; qt < 4; qt++) {
#pragma unroll
            for (int pt = 0; pt < 4; pt++) {
                acc[qt][pt] = __builtin_amdgcn_mfma_f32_16x16x32_f16(
                    ah[qt], bh[pt], acc[qt][pt], 0, 0, 0);
                acc[qt][pt] = __builtin_amdgcn_mfma_f32_16x16x32_f16(
                    ah[qt], bl[pt], acc[qt][pt], 0, 0, 0);
            }
        }
        __syncthreads();   // drains prefetch vmcnt + all waves done with buf
    }
#undef STAGE

    // ---------------- epilogue: coord term + MLP + store -------------------
    // uniform weights -> SGPRs
    float Wa[H_], Wb[H_], Bb[H_], Wo[H_];
#pragma unroll
    for (int h = 0; h < H_; h++) {
        Wa[h] = pW1[2 * h]; Wb[h] = pW1[2 * h + 1];
        Bb[h] = pb1[h];     Wo[h] = pW2[h];
    }
    float base2 = pb2[0];

    float px[4], py[4], pz[4], pn2[4];
    int pg[4];
#pragma unroll
    for (int pt = 0; pt < 4; pt++) {
        int p = pBase + wp + pt * 16 + fr;
        pg[pt] = p;
        const float* pp = pc + ((size_t)(b * N_ + p)) * 3;
        px[pt] = pp[0]; py[pt] = pp[1]; pz[pt] = pp[2];
        pn2[pt] = px[pt] * px[pt] + py[pt] * py[pt] + pz[pt] * pz[pt];
    }
#pragma unroll
    for (int qt = 0; qt < 4; qt++) {
        float qx[4], qy[4], qz[4], qq2[4];
        int q0 = qBase + wq + qt * 16 + kg * 4;
#pragma unroll
        for (int r = 0; r < 4; r++) {
            const float* qp = qc + ((size_t)(b * N_ + q0 + r)) * 3;
            qx[r] = qp[0]; qy[r] = qp[1]; qz[r] = qp[2];
            qq2[r] = qx[r] * qx[r] + qy[r] * qy[r] + qz[r] * qz[r];
        }
#pragma unroll
        for (int pt = 0; pt < 4; pt++) {
            f32x4 cval = acc[qt][pt];
            float w2v[4];
#pragma unroll
            for (int r = 0; r < 4; r++) {
                float d2 = qq2[r] + pn2[pt]
                         - 2.f * (qx[r] * px[pt] + qy[r] * py[pt] + qz[r] * pz[pt]);
                w2v[r] = -fmaxf(d2, 0.f);
            }
            // paired MLP: two float2 lanes -> v_pk_fma_f32
#pragma unroll
            for (int pr = 0; pr < 2; pr++) {
                f32x2 w1p = { cval[2 * pr], cval[2 * pr + 1] };
                f32x2 w2p = { w2v[2 * pr], w2v[2 * pr + 1] };
                f32x2 outp = { base2, base2 };
#pragma unroll
                for (int h = 0; h < H_; h++) {
                    f32x2 t = w1p * Wa[h] + w2p * Wb[h] + Bb[h];
                    t = __builtin_elementwise_max(t, (f32x2){0.f, 0.f});
                    outp += Wo[h] * t;
                }
                w_out[((size_t)(b * N_ + q0 + 2 * pr)) * N_ + pg[pt]]     = outp.x;
                w_out[((size_t)(b * N_ + q0 + 2 * pr + 1)) * N_ + pg[pt]] = outp.y;
            }
        }
    }
}

// ---------------------------------------------------------------------------
// Kernel 3: approx top-32 candidates (ballot threshold select) -> exact fp64
// rescore -> exact top-8 via LDS rank -> softmax + gather + pool.
// One wave per (b,q) row, 4 rows per block.  (unchanged — verified)
// ---------------------------------------------------------------------------
__global__ __launch_bounds__(256)
void topk_kernel(const float* __restrict__ w, const float* __restrict__ f1,
                 const float* __restrict__ f2,
                 const float* __restrict__ pc, const float* __restrict__ qc,
                 const float* __restrict__ pW1, const float* __restrict__ pb1,
                 const float* __restrict__ pW2, const float* __restrict__ pb2,
                 float* __restrict__ f_out, float* __restrict__ idx_out) {
    __shared__ int    s_cand[4][CAND];
    __shared__ double s_val[4][CAND];
    __shared__ int    s_idx[4][CAND];
    __shared__ double s_rv[4][K_];
    __shared__ int    s_ri[4][K_];

    int tid  = threadIdx.x;
    int wix  = tid >> 6;
    int lane = tid & 63;
    int row  = blockIdx.x * 4 + wix;          // grid is exact: row < B_*N_
    int b    = row >> 11;
    const float* wrow = w + (size_t)row * N_;

    // ---- phase 1: per-lane sorted top-8 scan of approx scores ----
    float tv[K_];
    int   ti[K_];
#pragma unroll
    for (int s = 0; s < K_; s++) { tv[s] = -INFINITY; ti[s] = 0x7fffffff; }
    for (int j = 0; j < N_ / 256; j++) {
        float4 v4 = *(const float4*)(wrow + lane * 4 + j * 256);
        float vv[4] = {v4.x, v4.y, v4.z, v4.w};
#pragma unroll
        for (int c = 0; c < 4; c++) {
            float v = vv[c];
            if (v > tv[K_ - 1]) {
                int idx = lane * 4 + j * 256 + c;
                tv[K_ - 1] = v; ti[K_ - 1] = idx;
#pragma unroll
                for (int s = K_ - 1; s > 0; s--) {
                    if (tv[s] > tv[s - 1]) {
                        float tf = tv[s]; tv[s] = tv[s - 1]; tv[s - 1] = tf;
                        int tn = ti[s]; ti[s] = ti[s - 1]; ti[s - 1] = tn;
                    }
                }
            }
        }
    }

    // ---- phase 2: wave top-32 via ballot binary search on uint keys ----
    unsigned uk[K_];
#pragma unroll
    for (int s = 0; s < K_; s++) uk[s] = ford(tv[s]);

    unsigned T = 0;
    for (int bit = 31; bit >= 0; --bit) {
        unsigned c = T | (1u << bit);
        int cnt = 0;
#pragma unroll
        for (int s = 0; s < K_; s++)
            cnt += __popcll(__ballot(uk[s] >= c));
        if (cnt >= CAND) T = c;   // keep bit: still >= 32 values above
    }
    // T is now the CAND-th largest key; compact indices of values >= T.
    unsigned long long below = (1ull << lane) - 1ull;
    int total = 0;
#pragma unroll
    for (int s = 0; s < K_; s++) {
        unsigned long long m = __ballot(uk[s] >= T);
        int pos = total + __popcll(m & below);
        if (uk[s] >= T && pos < CAND) s_cand[wix][pos] = ti[s];
        total += __popcll(m);
    }
    __syncthreads();

    // ---- phase 3: parallel exact fp64 rescore ----
    int sl = lane & 7;
    int gr = lane >> 3;
    const float* f2r = f2 + (size_t)row * D_ + sl * 32;
    float4 a4[8];
#pragma unroll
    for (int t = 0; t < 8; t++) a4[t] = *(const float4*)(f2r + t * 4);

    double daa = 0.0;
#pragma unroll
    for (int t = 0; t < 8; t++) {
        daa += (double)a4[t].x * (double)a4[t].x;
        daa += (double)a4[t].y * (double)a4[t].y;
        daa += (double)a4[t].z * (double)a4[t].z;
        daa += (double)a4[t].w * (double)a4[t].w;
    }
#pragma unroll
    for (int off = 1; off < 8; off <<= 1) daa += __shfl_xor(daa, off, 64);
    double inv_a = 1.0 / (sqrt(daa) + 1e-8);

    double mydab = 0.0, mydbb = 0.0;
    int myci = 0x7fffffff;
#pragma unroll
    for (int r = 0; r < 4; r++) {
        int cj = s_cand[wix][8 * r + gr];
        const float* f1r = f1 + ((size_t)(b * N_ + cj)) * D_ + sl * 32;
        double sA = 0.0, sB = 0.0;
#pragma unroll
        for (int t = 0; t < 8; t++) {
            float4 b4 = *(const float4*)(f1r + t * 4);
            double b0 = b4.x, b1 = b4.y, b2 = b4.z, b3 = b4.w;
            sA += (double)a4[t].x * b0; sB += b0 * b0;
            sA += (double)a4[t].y * b1; sB += b1 * b1;
            sA += (double)a4[t].z * b2; sB += b2 * b2;
            sA += (double)a4[t].w * b3; sB += b3 * b3;
        }
#pragma unroll
        for (int off = 1; off < 8; off <<= 1) {
            sA += __shfl_xor(sA, off, 64);
            sB += __shfl_xor(sB, off, 64);
        }
        if (sl == r) { mydab = sA; mydbb = sB; myci = cj; }
    }

    double ex = -INFINITY;
    int    ei = 0x7fffffff;
    if (sl < 4) {
        ei = myci;
        double w1d = mydab * inv_a * (1.0 / (sqrt(mydbb) + 1e-8));
        const float* qp = qc + (size_t)row * 3;
        double qx = qp[0], qy = qp[1], qz = qp[2];
        const float* pp = pc + ((size_t)(b * N_ + myci)) * 3;
        double px = pp[0], py = pp[1], pz = pp[2];
        double d2 = (qx * qx + qy * qy + qz * qz) + (px * px + py * py + pz * pz)
                  - 2.0 * (qx * px + qy * py + qz * pz);
        double w2d = -fmax(d2, 0.0);
        double out = (double)pb2[0];
#pragma unroll
        for (int h = 0; h < H_; h++) {
            double t = (double)pW1[2 * h] * w1d + (double)pW1[2 * h + 1] * w2d
                     + (double)pb1[h];
            out += (double)pW2[h] * fmax(t, 0.0);
        }
        ex = out;
    }

    // ---- phase 4: exact top-8 via LDS rank (desc, smaller idx tie) ----
    int slot = gr * 4 + sl;                  // 0..31 for scorer lanes
    if (sl < 4) {
        s_val[wix][slot] = ex;
        s_idx[wix][slot] = ei;
    }
    asm volatile("s_waitcnt lgkmcnt(0)" ::: "memory");   // in-wave LDS drain
    if (sl < 4) {
        int rank = 0;
#pragma unroll
        for (int j = 0; j < CAND; j++) {
            double vj = s_val[wix][j];
            int    ij = s_idx[wix][j];
            rank += (vj > ex || (vj == ex && ij < ei)) ? 1 : 0;
        }
        if (rank < K_) { s_rv[wix][rank] = ex; s_ri[wix][rank] = ei; }
    }
    asm volatile("s_waitcnt lgkmcnt(0)" ::: "memory");   // in-wave LDS drain

    double outv[K_];
    int    outi[K_];
#pragma unroll
    for (int r = 0; r < K_; r++) { outv[r] = s_rv[wix][r]; outi[r] = s_ri[wix][r]; }

    // ---- phase 5: softmax + gather + pool + write ----
    float m = (float)outv[0];
    float e[K_], s = 0.f;
#pragma unroll
    for (int r = 0; r < K_; r++) { e[r] = expf((float)outv[r] - m); s += e[r]; }
    float inv_s = 1.f / s;

    const float* f1b = f1 + ((size_t)b * N_) * D_;
    size_t obase = (size_t)row * (2 * D_);
#pragma unroll
    for (int jd = 0; jd < D_ / 64; jd++) {
        int d = lane + 64 * jd;
        float accv = 0.f, mx = -INFINITY;
#pragma unroll
        for (int r = 0; r < K_; r++) {
            float x = f1b[(size_t)outi[r] * D_ + d];
            accv += (e[r] * inv_s) * x;
            mx = fmaxf(mx, x);
        }
        f_out[obase + d]      = accv;
        f_out[obase + D_ + d] = mx;
    }
    if (lane == 0) {
#pragma unroll
        for (int r = 0; r < K_; r++) idx_out[(size_t)row * K_ + r] = (float)outi[r];
    }
}

// ---------------------------------------------------------------------------
extern "C" void kernel_launch(void* const* d_in, const int* in_sizes, int n_in,
                              void* d_out, int out_size, void* d_ws, size_t ws_size,
                              hipStream_t stream) {
    const float* f1 = (const float*)d_in[0];
    const float* f2 = (const float*)d_in[1];
    const float* pc = (const float*)d_in[2];
    const float* qc = (const float*)d_in[3];
    const float* W1 = (const float*)d_in[4];
    const float* b1 = (const float*)d_in[5];
    const float* W2 = (const float*)d_in[6];
    const float* b2 = (const float*)d_in[7];

    float* out     = (float*)d_out;
    float* f_out   = out;                                   // [B,N,2D]
    float* idx_out = f_out + (size_t)B_ * N_ * 2 * D_;      // [B,N,K] as float
    float* w_out   = idx_out + (size_t)B_ * N_ * K_;        // [B,N,N]

    // Scratch fp16 panels live in the f_out region (33,554,432 B >= 3 arrays
    // of B*N*D ushorts = 25.2 MB).  f_out is only written by topk_kernel
    // afterwards, so this is safe under stream ordering.
    unsigned short* s1h = (unsigned short*)f_out;           // f1 hi (B side)
    unsigned short* s1l = s1h + (size_t)B_ * N_ * D_;       // f1 lo (B side)
    unsigned short* s2h = s1l + (size_t)B_ * N_ * D_;       // f2 hi (A side)

    prep_kernel<<<(2 * B_ * N_) / 4, 256, 0, stream>>>(f1, f2, s1h, s1l, s2h);

    dim3 g2(N_ / BM, N_ / BM, B_);
    gemm_mlp_kernel<<<g2, 256, 0, stream>>>(s2h, s1h, s1l, pc, qc,
                                            W1, b1, W2, b2, w_out);

    topk_kernel<<<(B_ * N_) / 4, 256, 0, stream>>>(w_out, f1, f2, pc, qc,
                                                   W1, b1, W2, b2,
                                                   f_out, idx_out);
}

// Round 5
// 388.307 us; speedup vs baseline: 3.1888x; 1.0674x over previous
//
#include <hip/hip_runtime.h>
#include <math.h>

// Problem constants (fixed by setup_inputs)
constexpr int B_ = 8;
constexpr int N_ = 2048;
constexpr int D_ = 256;
constexpr int H_ = 16;
constexpr int K_ = 8;
constexpr int POOL = 64;   // candidate pool capacity (threshold select)
constexpr int PSEL = 24;   // select T = PSEL-th largest lane-max (pool >= PSEL)

constexpr int BM = 128;    // tile rows (q and p)
constexpr int BK = 32;     // k chunk per stage (1 MFMA K-step), double-buffered

typedef _Float16 f16x8 __attribute__((ext_vector_type(8)));
typedef float    f32x4 __attribute__((ext_vector_type(4)));
typedef float    f32x2 __attribute__((ext_vector_type(2)));

// address-space-qualified pointers for global_load_lds
typedef __attribute__((address_space(3))) unsigned int       lds_u32_t;
typedef __attribute__((address_space(1))) const unsigned int glb_u32_t;

__device__ __forceinline__ void g2l16(const void* g, void* l) {
    // 16B direct global->LDS (dest = wave-uniform base + lane*16)
    __builtin_amdgcn_global_load_lds((glb_u32_t*)g, (lds_u32_t*)l, 16, 0, 0);
}

// order-preserving float -> uint map: a > b  <=>  ford(a) > ford(b)
__device__ __forceinline__ unsigned ford(float f) {
    unsigned u = __float_as_uint(f);
    return (u & 0x80000000u) ? ~u : (u | 0x80000000u);
}
__device__ __forceinline__ float unford(unsigned t) {
    return (t & 0x80000000u) ? __uint_as_float(t & 0x7FFFFFFFu)
                             : __uint_as_float(~t);
}

__device__ __forceinline__ unsigned pk16(_Float16 a, _Float16 b) {
    unsigned short ua = __builtin_bit_cast(unsigned short, a);
    unsigned short ub = __builtin_bit_cast(unsigned short, b);
    return (unsigned)ua | ((unsigned)ub << 16);
}

// fp32*scale -> fp16 hi (RNE) + fp16 lo (RNE residual), packed pairs
__device__ inline void split4_f16(float4 v, float s, uint2& hi, uint2& lo) {
    float a = v.x * s, b = v.y * s, c = v.z * s, d = v.w * s;
    _Float16 ha = (_Float16)a, hb = (_Float16)b;
    _Float16 hc = (_Float16)c, hd = (_Float16)d;
    _Float16 la = (_Float16)(a - (float)ha), lb = (_Float16)(b - (float)hb);
    _Float16 lc = (_Float16)(c - (float)hc), ld = (_Float16)(d - (float)hd);
    hi.x = pk16(ha, hb); hi.y = pk16(hc, hd);
    lo.x = pk16(la, lb); lo.y = pk16(lc, ld);
}

// ---------------------------------------------------------------------------
// Kernel 1 (prep): fp32 -> normalized fp16 split, stored tile-panel-major and
// PRE-SWIZZLED so a linear global_load_lds copy yields a bank-floor LDS
// layout.  f1 (B side): hi + lo + fp64 inverse norm.  f2 (A side): hi only.
// Tile = [128 rows][32 k-elems] fp16 = 8 KiB; tile idx = (row/128)*8+(k/32).
// Within a row (64 B, 4 slots of 16 B): slot' = slot ^ ((row>>1) & 3).
// ---------------------------------------------------------------------------
__global__ __launch_bounds__(256)
void prep_kernel(const float* __restrict__ f1, const float* __restrict__ f2,
                 unsigned short* __restrict__ s1h, unsigned short* __restrict__ s1l,
                 unsigned short* __restrict__ s2h, double* __restrict__ dinv1) {
    int gid  = blockIdx.x * blockDim.x + threadIdx.x;
    int wave = gid >> 6;
    int lane = gid & 63;
    if (wave >= 2 * B_ * N_) return;
    bool is1 = wave < B_ * N_;
    int r = is1 ? wave : wave - B_ * N_;

    const float* src = (is1 ? f1 : f2) + (size_t)r * D_;
    float4 v = *(const float4*)(src + lane * 4);
    float ss = v.x * v.x + v.y * v.y + v.z * v.z + v.w * v.w;
#pragma unroll
    for (int off = 32; off > 0; off >>= 1) ss += __shfl_xor(ss, off, 64);
    float inv = 1.0f / (sqrtf(ss) + 1e-8f);

    uint2 hi, lo;
    split4_f16(v, inv, hi, lo);

    int panel = r >> 7, rloc = r & 127;
    int s     = lane >> 1;                   // 16B slot index 0..31 (256 elems)
    int chunk = s >> 2;                      // which 32-elem k-chunk (tile) 0..7
    int sl    = (s & 3) ^ ((rloc >> 1) & 3); // swizzled slot within 64B row
    int half  = lane & 1;
    size_t idx = ((size_t)(panel * 8 + chunk) << 12)   // tile * 4096 ushorts
               + (size_t)rloc * 32 + sl * 8 + half * 4;
    if (is1) {
        *(uint2*)&s1h[idx] = hi;
        *(uint2*)&s1l[idx] = lo;
        // exact fp64 inverse norm of this f1 row (hoisted out of topk's
        // rescore: was recomputed 32x per row there)
        double dss = (double)v.x * v.x + (double)v.y * v.y
                   + (double)v.z * v.z + (double)v.w * v.w;
#pragma unroll
        for (int off = 32; off > 0; off >>= 1) dss += __shfl_xor(dss, off, 64);
        if (lane == 0) dinv1[r] = 1.0 / (sqrt(dss) + 1e-8);
    } else {
        *(uint2*)&s2h[idx] = hi;
    }
}

// ---------------------------------------------------------------------------
// Kernel 2: MFMA cosine-sim GEMM (asymmetric fp16 2-term: hA*(hB+lB)) +
// coord dist + MLP.  BK=32 double-buffered, 2-phase prefetch, pk-fma MLP.
// (unchanged from round 4 — verified)
// ---------------------------------------------------------------------------
__global__ __launch_bounds__(256, 3)
void gemm_mlp_kernel(const unsigned short* __restrict__ aH0,  // f2 hi (A, q)
                     const unsigned short* __restrict__ bH0,  // f1 hi (B, p)
                     const unsigned short* __restrict__ bL0,  // f1 lo (B, p)
                     const float* __restrict__ pc, const float* __restrict__ qc,
                     const float* __restrict__ pW1, const float* __restrict__ pb1,
                     const float* __restrict__ pW2, const float* __restrict__ pb2,
                     float* __restrict__ w_out) {
    // 2 buffers x 3 tiles (Ahi | Bhi | Blo) x 8 KiB = 48 KiB
    __shared__ unsigned short ldsbuf[2 * 3 * 4096];

    int tid = threadIdx.x;
    // bijective XCD chunking swizzle within each z-slice (256 blocks, 256%8==0)
    int l  = blockIdx.x + (blockIdx.y << 4);
    int ls = ((l & 7) << 5) | (l >> 3);
    int pBase = (ls & 15) * BM;
    int qBase = (ls >> 4) * BM;
    int b = blockIdx.z;

    int lane = tid & 63;
    int wv   = tid >> 6;
    int wq = (wv >> 1) * 64;
    int wp = (wv & 1) * 64;
    int fr = lane & 15;
    int kg = lane >> 4;

    const int Apanel8 = ((b * N_ + qBase) >> 7) * 8;   // 8 KiB tile idx base
    const int Bpanel8 = ((b * N_ + pBase) >> 7) * 8;

    char* ldsB = (char*)&ldsbuf[0];
    const int wlo = (wv << 11) + (lane << 4);   // per-lane global byte offset
    const int wdo = (wv << 11);                 // wave-uniform LDS byte offset
    const int cw  = (kg ^ ((fr >> 1) & 3)) << 4;  // swizzled 16B slot

    f32x4 acc[4][4] = {};

#define STAGE(buf, c)                                                          \
    {                                                                          \
        const char* aH = (const char*)aH0 + ((size_t)(Apanel8 + (c)) << 13);   \
        const char* bH = (const char*)bH0 + ((size_t)(Bpanel8 + (c)) << 13);   \
        const char* bL = (const char*)bL0 + ((size_t)(Bpanel8 + (c)) << 13);   \
        char* dst = ldsB + (buf) * 24576;                                      \
        _Pragma("unroll")                                                      \
        for (int i = 0; i < 2; i++) {                                          \
            int o = i << 10;                                                   \
            g2l16(aH + wlo + o, dst + 0     + wdo + o);                        \
            g2l16(bH + wlo + o, dst + 8192  + wdo + o);                        \
            g2l16(bL + wlo + o, dst + 16384 + wdo + o);                        \
        }                                                                      \
    }

    STAGE(0, 0);
    __syncthreads();                       // drain: buf0 ready

#pragma unroll
    for (int c = 0; c < 8; c++) {          // 8 K-chunks of 32
        if (c < 7) STAGE((c + 1) & 1, c + 1);   // prefetch next (other buffer)

        char* base = ldsB + (c & 1) * 24576;
        f16x8 ah[4], bh[4], bl[4];
#pragma unroll
        for (int t = 0; t < 4; t++) {
            int ra = (wq + t * 16 + fr) * 64;
            int rb = (wp + t * 16 + fr) * 64;
            ah[t] = *(const f16x8*)(base + 0     + ra + cw);
            bh[t] = *(const f16x8*)(base + 8192  + rb + cw);
            bl[t] = *(const f16x8*)(base + 16384 + rb + cw);
        }
#pragma unroll
        for (int qt = 0; qt < 4; qt++) {
#pragma unroll
            for (int pt = 0; pt < 4; pt++) {
                acc[qt][pt] = __builtin_amdgcn_mfma_f32_16x16x32_f16(
                    ah[qt], bh[pt], acc[qt][pt], 0, 0, 0);
                acc[qt][pt] = __builtin_amdgcn_mfma_f32_16x16x32_f16(
                    ah[qt], bl[pt], acc[qt][pt], 0, 0, 0);
            }
        }
        __syncthreads();   // drains prefetch vmcnt + all waves done with buf
    }
#undef STAGE

    // ---------------- epilogue: coord term + MLP + store -------------------
    float Wa[H_], Wb[H_], Bb[H_], Wo[H_];
#pragma unroll
    for (int h = 0; h < H_; h++) {
        Wa[h] = pW1[2 * h]; Wb[h] = pW1[2 * h + 1];
        Bb[h] = pb1[h];     Wo[h] = pW2[h];
    }
    float base2 = pb2[0];

    float px[4], py[4], pz[4], pn2[4];
    int pg[4];
#pragma unroll
    for (int pt = 0; pt < 4; pt++) {
        int p = pBase + wp + pt * 16 + fr;
        pg[pt] = p;
        const float* pp = pc + ((size_t)(b * N_ + p)) * 3;
        px[pt] = pp[0]; py[pt] = pp[1]; pz[pt] = pp[2];
        pn2[pt] = px[pt] * px[pt] + py[pt] * py[pt] + pz[pt] * pz[pt];
    }
#pragma unroll
    for (int qt = 0; qt < 4; qt++) {
        float qx[4], qy[4], qz[4], qq2[4];
        int q0 = qBase + wq + qt * 16 + kg * 4;
#pragma unroll
        for (int r = 0; r < 4; r++) {
            const float* qp = qc + ((size_t)(b * N_ + q0 + r)) * 3;
            qx[r] = qp[0]; qy[r] = qp[1]; qz[r] = qp[2];
            qq2[r] = qx[r] * qx[r] + qy[r] * qy[r] + qz[r] * qz[r];
        }
#pragma unroll
        for (int pt = 0; pt < 4; pt++) {
            f32x4 cval = acc[qt][pt];
            float w2v[4];
#pragma unroll
            for (int r = 0; r < 4; r++) {
                float d2 = qq2[r] + pn2[pt]
                         - 2.f * (qx[r] * px[pt] + qy[r] * py[pt] + qz[r] * pz[pt]);
                w2v[r] = -fmaxf(d2, 0.f);
            }
#pragma unroll
            for (int pr = 0; pr < 2; pr++) {
                f32x2 w1p = { cval[2 * pr], cval[2 * pr + 1] };
                f32x2 w2p = { w2v[2 * pr], w2v[2 * pr + 1] };
                f32x2 outp = { base2, base2 };
#pragma unroll
                for (int h = 0; h < H_; h++) {
                    f32x2 t = w1p * Wa[h] + w2p * Wb[h] + Bb[h];
                    t = __builtin_elementwise_max(t, (f32x2){0.f, 0.f});
                    outp += Wo[h] * t;
                }
                w_out[((size_t)(b * N_ + q0 + 2 * pr)) * N_ + pg[pt]]     = outp.x;
                w_out[((size_t)(b * N_ + q0 + 2 * pr + 1)) * N_ + pg[pt]] = outp.y;
            }
        }
    }
}

// ---------------------------------------------------------------------------
// Kernel 3: threshold candidate select (T = 24th-largest lane-max; pool is
// provably >= the approx top-24) -> exact fp64 rescore (precomputed f1 norms)
// -> exact top-8 via LDS rank -> softmax + gather + pool.
// One wave per (b,q) row, 4 rows per block.
// ---------------------------------------------------------------------------
__global__ __launch_bounds__(256)
void topk_kernel(const float* __restrict__ w, const float* __restrict__ f1,
                 const float* __restrict__ f2,
                 const float* __restrict__ pc, const float* __restrict__ qc,
                 const float* __restrict__ pW1, const float* __restrict__ pb1,
                 const float* __restrict__ pW2, const float* __restrict__ pb2,
                 const double* __restrict__ dinv1,
                 float* __restrict__ f_out, float* __restrict__ idx_out) {
    __shared__ int    s_cand[4][POOL];
    __shared__ double s_val[4][POOL];
    __shared__ int    s_idx[4][POOL];
    __shared__ double s_rv[4][K_];
    __shared__ int    s_ri[4][K_];

    int tid  = threadIdx.x;
    int wix  = tid >> 6;
    int lane = tid & 63;
    int row  = blockIdx.x * 4 + wix;          // grid is exact: row < B_*N_
    int b    = row >> 11;
    const float* wrow = w + (size_t)row * N_;

    // ---- phase 1: vector scan, per-lane max only (no insertion chains) ----
    float4 v4s[8];
    float mymax = -INFINITY;
#pragma unroll
    for (int j = 0; j < 8; j++) {
        v4s[j] = *(const float4*)(wrow + lane * 4 + j * 256);
        mymax = fmaxf(mymax,
                 fmaxf(fmaxf(v4s[j].x, v4s[j].y), fmaxf(v4s[j].z, v4s[j].w)));
    }

    // ---- phase 2a: T = PSEL-th largest of the 64 lane-maxes (1 ballot/bit).
    // Guarantees: #(values >= T) >= PSEL, and every global top-PSEL value >= T.
    unsigned mk = ford(mymax);
    unsigned T = 0;
    for (int bit = 31; bit >= 0; --bit) {
        unsigned c = T | (1u << bit);
        if (__popcll(__ballot(mk >= c)) >= PSEL) T = c;
    }
    float Tf = unford(T);

    // ---- phase 2b: ballot prefix compaction of {v >= Tf} (first POOL kept,
    // index-ordered drops match jax's smaller-index tie preference) ----
    unsigned long long below = (1ull << lane) - 1ull;
    int total = 0;
#pragma unroll
    for (int j = 0; j < 8; j++) {
        float vv[4] = {v4s[j].x, v4s[j].y, v4s[j].z, v4s[j].w};
#pragma unroll
        for (int c = 0; c < 4; c++) {
            bool in = vv[c] >= Tf;
            unsigned long long m = __ballot(in);
            if (in) {
                int pos = total + __popcll(m & below);
                if (pos < POOL) s_cand[wix][pos] = lane * 4 + j * 256 + c;
            }
            total += __popcll(m);
        }
    }
    int ncand = total < POOL ? total : POOL;
    asm volatile("s_waitcnt lgkmcnt(0)" ::: "memory");   // in-wave LDS drain

    // ---- phase 3: parallel exact fp64 rescore (f1 norms precomputed) ----
    int sl = lane & 7;
    int gr = lane >> 3;
    const float* f2r = f2 + (size_t)row * D_ + sl * 32;
    float4 a4[8];
#pragma unroll
    for (int t = 0; t < 8; t++) a4[t] = *(const float4*)(f2r + t * 4);

    double daa = 0.0;
#pragma unroll
    for (int t = 0; t < 8; t++) {
        daa += (double)a4[t].x * (double)a4[t].x;
        daa += (double)a4[t].y * (double)a4[t].y;
        daa += (double)a4[t].z * (double)a4[t].z;
        daa += (double)a4[t].w * (double)a4[t].w;
    }
#pragma unroll
    for (int off = 1; off < 8; off <<= 1) daa += __shfl_xor(daa, off, 64);
    double inv_a = 1.0 / (sqrt(daa) + 1e-8);

    double mydab = 0.0;
    int myci = 0;
    int NR = (ncand + 7) >> 3;               // <= 8 rounds (wave-uniform)
    for (int r = 0; r < NR; r++) {
        int k = 8 * r + gr;
        int cj = (k < ncand) ? s_cand[wix][k] : 0;
        const float* f1r = f1 + ((size_t)(b * N_ + cj)) * D_ + sl * 32;
        double sA = 0.0;
#pragma unroll
        for (int t = 0; t < 8; t++) {
            float4 b4 = *(const float4*)(f1r + t * 4);
            sA += (double)a4[t].x * (double)b4.x;
            sA += (double)a4[t].y * (double)b4.y;
            sA += (double)a4[t].z * (double)b4.z;
            sA += (double)a4[t].w * (double)b4.w;
        }
#pragma unroll
        for (int off = 1; off < 8; off <<= 1) sA += __shfl_xor(sA, off, 64);
        if (sl == r) { mydab = sA; myci = cj; }
    }

    // lane (gr, sl) owns candidate k = 8*sl + gr
    int myk = 8 * sl + gr;
    double ex = -INFINITY;
    int    ei = 0x7fffffff;
    if (myk < ncand) {
        ei = myci;
        double w1d = mydab * inv_a * dinv1[b * N_ + myci];
        const float* qp = qc + (size_t)row * 3;
        double qx = qp[0], qy = qp[1], qz = qp[2];
        const float* pp = pc + ((size_t)(b * N_ + myci)) * 3;
        double px = pp[0], py = pp[1], pz = pp[2];
        double d2 = (qx * qx + qy * qy + qz * qz) + (px * px + py * py + pz * pz)
                  - 2.0 * (qx * px + qy * py + qz * pz);
        double w2d = -fmax(d2, 0.0);
        double out = (double)pb2[0];
#pragma unroll
        for (int h = 0; h < H_; h++) {
            double t = (double)pW1[2 * h] * w1d + (double)pW1[2 * h + 1] * w2d
                     + (double)pb1[h];
            out += (double)pW2[h] * fmax(t, 0.0);
        }
        ex = out;
    }

    // ---- phase 4: exact top-8 via LDS rank (desc, smaller idx tie) ----
    s_val[wix][myk] = ex;
    s_idx[wix][myk] = ei;
    asm volatile("s_waitcnt lgkmcnt(0)" ::: "memory");   // in-wave LDS drain
    {
        int rank = 0;
#pragma unroll
        for (int j = 0; j < POOL; j++) {
            double vj = s_val[wix][j];
            int    ij = s_idx[wix][j];
            rank += (vj > ex || (vj == ex && ij < ei)) ? 1 : 0;
        }
        if (rank < K_) { s_rv[wix][rank] = ex; s_ri[wix][rank] = ei; }
    }
    asm volatile("s_waitcnt lgkmcnt(0)" ::: "memory");   // in-wave LDS drain

    double outv[K_];
    int    outi[K_];
#pragma unroll
    for (int r = 0; r < K_; r++) { outv[r] = s_rv[wix][r]; outi[r] = s_ri[wix][r]; }

    // ---- phase 5: softmax + gather + pool + write ----
    float m = (float)outv[0];
    float e[K_], s = 0.f;
#pragma unroll
    for (int r = 0; r < K_; r++) { e[r] = expf((float)outv[r] - m); s += e[r]; }
    float inv_s = 1.f / s;

    const float* f1b = f1 + ((size_t)b * N_) * D_;
    size_t obase = (size_t)row * (2 * D_);
#pragma unroll
    for (int jd = 0; jd < D_ / 64; jd++) {
        int d = lane + 64 * jd;
        float accv = 0.f, mx = -INFINITY;
#pragma unroll
        for (int r = 0; r < K_; r++) {
            float x = f1b[(size_t)outi[r] * D_ + d];
            accv += (e[r] * inv_s) * x;
            mx = fmaxf(mx, x);
        }
        f_out[obase + d]      = accv;
        f_out[obase + D_ + d] = mx;
    }
    if (lane == 0) {
#pragma unroll
        for (int r = 0; r < K_; r++) idx_out[(size_t)row * K_ + r] = (float)outi[r];
    }
}

// ---------------------------------------------------------------------------
extern "C" void kernel_launch(void* const* d_in, const int* in_sizes, int n_in,
                              void* d_out, int out_size, void* d_ws, size_t ws_size,
                              hipStream_t stream) {
    const float* f1 = (const float*)d_in[0];
    const float* f2 = (const float*)d_in[1];
    const float* pc = (const float*)d_in[2];
    const float* qc = (const float*)d_in[3];
    const float* W1 = (const float*)d_in[4];
    const float* b1 = (const float*)d_in[5];
    const float* W2 = (const float*)d_in[6];
    const float* b2 = (const float*)d_in[7];

    float* out     = (float*)d_out;
    float* f_out   = out;                                   // [B,N,2D]
    float* idx_out = f_out + (size_t)B_ * N_ * 2 * D_;      // [B,N,K] as float
    float* w_out   = idx_out + (size_t)B_ * N_ * K_;        // [B,N,N]

    // Scratch fp16 panels live in the f_out region (33,554,432 B >= 3 arrays
    // of B*N*D ushorts = 25.2 MB).  f_out is only written by topk_kernel
    // afterwards, so this is safe under stream ordering.
    unsigned short* s1h = (unsigned short*)f_out;           // f1 hi (B side)
    unsigned short* s1l = s1h + (size_t)B_ * N_ * D_;       // f1 lo (B side)
    unsigned short* s2h = s1l + (size_t)B_ * N_ * D_;       // f2 hi (A side)

    // fp64 f1 inverse norms in d_ws: B*N doubles = 131072 B (same ws footprint
    // as the original session's norm buffers).
    double* dinv1 = (double*)d_ws;

    prep_kernel<<<(2 * B_ * N_) / 4, 256, 0, stream>>>(f1, f2, s1h, s1l, s2h,
                                                       dinv1);

    dim3 g2(N_ / BM, N_ / BM, B_);
    gemm_mlp_kernel<<<g2, 256, 0, stream>>>(s2h, s1h, s1l, pc, qc,
                                            W1, b1, W2, b2, w_out);

    topk_kernel<<<(B_ * N_) / 4, 256, 0, stream>>>(w_out, f1, f2, pc, qc,
                                                   W1, b1, W2, b2, dinv1,
                                                   f_out, idx_out);
}

// Round 6
// 378.973 us; speedup vs baseline: 3.2673x; 1.0246x over previous
//
#include <hip/hip_runtime.h>
#include <math.h>

// Problem constants (fixed by setup_inputs)
constexpr int B_ = 8;
constexpr int N_ = 2048;
constexpr int D_ = 256;
constexpr int H_ = 16;
constexpr int K_ = 8;
constexpr int POOL = 64;   // candidate pool capacity (threshold select)
constexpr int PSEL = 24;   // select T = PSEL-th largest lane-max (pool >= PSEL)

constexpr int BM = 128;    // tile rows (q and p)
constexpr int BK = 32;     // k chunk per stage (1 MFMA K-step), double-buffered

typedef _Float16 f16x8 __attribute__((ext_vector_type(8)));
typedef float    f32x4 __attribute__((ext_vector_type(4)));
typedef float    f32x2 __attribute__((ext_vector_type(2)));

// address-space-qualified pointers for global_load_lds
typedef __attribute__((address_space(3))) unsigned int       lds_u32_t;
typedef __attribute__((address_space(1))) const unsigned int glb_u32_t;

__device__ __forceinline__ void g2l16(const void* g, void* l) {
    // 16B direct global->LDS (dest = wave-uniform base + lane*16)
    __builtin_amdgcn_global_load_lds((glb_u32_t*)g, (lds_u32_t*)l, 16, 0, 0);
}

// order-preserving float -> uint map: a > b  <=>  ford(a) > ford(b)
__device__ __forceinline__ unsigned ford(float f) {
    unsigned u = __float_as_uint(f);
    return (u & 0x80000000u) ? ~u : (u | 0x80000000u);
}
__device__ __forceinline__ float unford(unsigned t) {
    return (t & 0x80000000u) ? __uint_as_float(t & 0x7FFFFFFFu)
                             : __uint_as_float(~t);
}

__device__ __forceinline__ unsigned pk16(_Float16 a, _Float16 b) {
    unsigned short ua = __builtin_bit_cast(unsigned short, a);
    unsigned short ub = __builtin_bit_cast(unsigned short, b);
    return (unsigned)ua | ((unsigned)ub << 16);
}

// fp32*scale -> fp16 hi (RNE) + fp16 lo (RNE residual), packed pairs
__device__ inline void split4_f16(float4 v, float s, uint2& hi, uint2& lo) {
    float a = v.x * s, b = v.y * s, c = v.z * s, d = v.w * s;
    _Float16 ha = (_Float16)a, hb = (_Float16)b;
    _Float16 hc = (_Float16)c, hd = (_Float16)d;
    _Float16 la = (_Float16)(a - (float)ha), lb = (_Float16)(b - (float)hb);
    _Float16 lc = (_Float16)(c - (float)hc), ld = (_Float16)(d - (float)hd);
    hi.x = pk16(ha, hb); hi.y = pk16(hc, hd);
    lo.x = pk16(la, lb); lo.y = pk16(lc, ld);
}

// ---------------------------------------------------------------------------
// Kernel 1 (prep): fp32 -> normalized fp16 split (tile-panel-major, swizzled
// for linear global_load_lds) + fp64 f1 inverse norms + fp16 hi/lo AUGMENTED
// coordinate rows for the w2 MFMA:
//   qaug = [qh_xyz, ql_xyz, qh_xyz, -|q|2_h, -|q|2_l, 1, 1, 0*19]
//   paug = [ph_xyz, ph_xyz, pl_xyz, 1, 1, -|p|2_h, -|p|2_l, 0*19]
//   dot(qaug,paug) = 2q.p - |q|2 - |p|2 = -d2   (err ~1e-6)
// ---------------------------------------------------------------------------
__global__ __launch_bounds__(256)
void prep_kernel(const float* __restrict__ f1, const float* __restrict__ f2,
                 const float* __restrict__ pcoord, const float* __restrict__ qcoord,
                 unsigned short* __restrict__ s1h, unsigned short* __restrict__ s1l,
                 unsigned short* __restrict__ s2h,
                 unsigned short* __restrict__ qaug, unsigned short* __restrict__ paug,
                 double* __restrict__ dinv1) {
    int gid  = blockIdx.x * blockDim.x + threadIdx.x;
    int wave = gid >> 6;
    int lane = gid & 63;
    if (wave >= 2 * B_ * N_) return;
    bool is1 = wave < B_ * N_;
    int r = is1 ? wave : wave - B_ * N_;

    const float* src = (is1 ? f1 : f2) + (size_t)r * D_;
    float4 v = *(const float4*)(src + lane * 4);
    float ss = v.x * v.x + v.y * v.y + v.z * v.z + v.w * v.w;
#pragma unroll
    for (int off = 32; off > 0; off >>= 1) ss += __shfl_xor(ss, off, 64);
    float inv = 1.0f / (sqrtf(ss) + 1e-8f);

    uint2 hi, lo;
    split4_f16(v, inv, hi, lo);

    int panel = r >> 7, rloc = r & 127;
    int s     = lane >> 1;                   // 16B slot index 0..31 (256 elems)
    int chunk = s >> 2;                      // which 32-elem k-chunk (tile) 0..7
    int sl    = (s & 3) ^ ((rloc >> 1) & 3); // swizzled slot within 64B row
    int half  = lane & 1;
    size_t idx = ((size_t)(panel * 8 + chunk) << 12)   // tile * 4096 ushorts
               + (size_t)rloc * 32 + sl * 8 + half * 4;
    if (is1) {
        *(uint2*)&s1h[idx] = hi;
        *(uint2*)&s1l[idx] = lo;
        double dss = (double)v.x * v.x + (double)v.y * v.y
                   + (double)v.z * v.z + (double)v.w * v.w;
#pragma unroll
        for (int off = 32; off > 0; off >>= 1) dss += __shfl_xor(dss, off, 64);
        if (lane == 0) dinv1[r] = 1.0 / (sqrt(dss) + 1e-8);
    } else {
        *(uint2*)&s2h[idx] = hi;
    }

    // augmented coord row (lane 0, scalar; tiny)
    if (lane == 0) {
        const float* cp = (is1 ? pcoord : qcoord) + (size_t)r * 3;
        float x = cp[0], y = cp[1], z = cp[2];
        const float s2 = 1.41421356237309515f;
        _Float16 xh = (_Float16)(s2 * x), yh = (_Float16)(s2 * y), zh = (_Float16)(s2 * z);
        _Float16 xl = (_Float16)(s2 * x - (float)xh);
        _Float16 yl = (_Float16)(s2 * y - (float)yh);
        _Float16 zl = (_Float16)(s2 * z - (float)zh);
        float nn = x * x + y * y + z * z;
        _Float16 nh = (_Float16)nn, nl = (_Float16)(nn - (float)nh);
        _Float16 one = (_Float16)1.0f;
        _Float16 mnh = -nh, mnl = -nl;
        unsigned short h[32];
#pragma unroll
        for (int i = 0; i < 32; i++) h[i] = 0;
#define US_(v) __builtin_bit_cast(unsigned short, v)
        if (is1) {   // p side
            h[0] = US_(xh); h[1] = US_(yh); h[2] = US_(zh);
            h[3] = US_(xh); h[4] = US_(yh); h[5] = US_(zh);
            h[6] = US_(xl); h[7] = US_(yl); h[8] = US_(zl);
            h[9] = US_(one); h[10] = US_(one);
            h[11] = US_(mnh); h[12] = US_(mnl);
        } else {     // q side
            h[0] = US_(xh); h[1] = US_(yh); h[2] = US_(zh);
            h[3] = US_(xl); h[4] = US_(yl); h[5] = US_(zl);
            h[6] = US_(xh); h[7] = US_(yh); h[8] = US_(zh);
            h[9] = US_(mnh); h[10] = US_(mnl);
            h[11] = US_(one); h[12] = US_(one);
        }
#undef US_
        unsigned short* dst = (is1 ? paug : qaug) + (size_t)r * 32;
#pragma unroll
        for (int i = 0; i < 4; i++) ((uint4*)dst)[i] = ((const uint4*)h)[i];
    }
}

// ---------------------------------------------------------------------------
// Kernel 2: MFMA cosine-sim GEMM (asymmetric fp16 2-term: hA*(hB+lB)) +
// w2 via augmented-coord MFMA + h-paired pk-f32 MLP.  BK=32 double-buffered,
// 2-phase prefetch (unchanged main loop).
// ---------------------------------------------------------------------------
__global__ __launch_bounds__(256, 3)
void gemm_mlp_kernel(const unsigned short* __restrict__ aH0,  // f2 hi (A, q)
                     const unsigned short* __restrict__ bH0,  // f1 hi (B, p)
                     const unsigned short* __restrict__ bL0,  // f1 lo (B, p)
                     const unsigned short* __restrict__ qaug,
                     const unsigned short* __restrict__ paug,
                     const float* __restrict__ pW1, const float* __restrict__ pb1,
                     const float* __restrict__ pW2, const float* __restrict__ pb2,
                     float* __restrict__ w_out) {
    // 2 buffers x 3 tiles (Ahi | Bhi | Blo) x 8 KiB = 48 KiB
    __shared__ unsigned short ldsbuf[2 * 3 * 4096];

    int tid = threadIdx.x;
    // bijective XCD chunking swizzle within each z-slice (256 blocks, 256%8==0)
    int l  = blockIdx.x + (blockIdx.y << 4);
    int ls = ((l & 7) << 5) | (l >> 3);
    int pBase = (ls & 15) * BM;
    int qBase = (ls >> 4) * BM;
    int b = blockIdx.z;

    int lane = tid & 63;
    int wv   = tid >> 6;
    int wq = (wv >> 1) * 64;
    int wp = (wv & 1) * 64;
    int fr = lane & 15;
    int kg = lane >> 4;

    const int Apanel8 = ((b * N_ + qBase) >> 7) * 8;   // 8 KiB tile idx base
    const int Bpanel8 = ((b * N_ + pBase) >> 7) * 8;

    char* ldsB = (char*)&ldsbuf[0];
    const int wlo = (wv << 11) + (lane << 4);   // per-lane global byte offset
    const int wdo = (wv << 11);                 // wave-uniform LDS byte offset
    const int cw  = (kg ^ ((fr >> 1) & 3)) << 4;  // swizzled 16B slot

    f32x4 acc[4][4] = {};

#define STAGE(buf, c)                                                          \
    {                                                                          \
        const char* aH = (const char*)aH0 + ((size_t)(Apanel8 + (c)) << 13);   \
        const char* bH = (const char*)bH0 + ((size_t)(Bpanel8 + (c)) << 13);   \
        const char* bL = (const char*)bL0 + ((size_t)(Bpanel8 + (c)) << 13);   \
        char* dst = ldsB + (buf) * 24576;                                      \
        _Pragma("unroll")                                                      \
        for (int i = 0; i < 2; i++) {                                          \
            int o = i << 10;                                                   \
            g2l16(aH + wlo + o, dst + 0     + wdo + o);                        \
            g2l16(bH + wlo + o, dst + 8192  + wdo + o);                        \
            g2l16(bL + wlo + o, dst + 16384 + wdo + o);                        \
        }                                                                      \
    }

    STAGE(0, 0);
    __syncthreads();                       // drain: buf0 ready

#pragma unroll
    for (int c = 0; c < 8; c++) {          // 8 K-chunks of 32
        if (c < 7) STAGE((c + 1) & 1, c + 1);   // prefetch next (other buffer)

        char* base = ldsB + (c & 1) * 24576;
        f16x8 ah[4], bh[4], bl[4];
#pragma unroll
        for (int t = 0; t < 4; t++) {
            int ra = (wq + t * 16 + fr) * 64;
            int rb = (wp + t * 16 + fr) * 64;
            ah[t] = *(const f16x8*)(base + 0     + ra + cw);
            bh[t] = *(const f16x8*)(base + 8192  + rb + cw);
            bl[t] = *(const f16x8*)(base + 16384 + rb + cw);
        }
#pragma unroll
        for (int qt = 0; qt < 4; qt++) {
#pragma unroll
            for (int pt = 0; pt < 4; pt++) {
                acc[qt][pt] = __builtin_amdgcn_mfma_f32_16x16x32_f16(
                    ah[qt], bh[pt], acc[qt][pt], 0, 0, 0);
                acc[qt][pt] = __builtin_amdgcn_mfma_f32_16x16x32_f16(
                    ah[qt], bl[pt], acc[qt][pt], 0, 0, 0);
            }
        }
        __syncthreads();   // drains prefetch vmcnt + all waves done with buf
    }
#undef STAGE

    // ---------------- epilogue: w2 MFMA + h-paired MLP + store -------------
    // weights as h-paired f32x2 (loop-invariant, natural pairs — no per-use
    // scalar->pair broadcast)
    f32x2 Wap[8], Wbp[8], Bbp[8], Wop[8];
#pragma unroll
    for (int hp = 0; hp < 8; hp++) {
        Wap[hp] = (f32x2){pW1[4 * hp],     pW1[4 * hp + 2]};
        Wbp[hp] = (f32x2){pW1[4 * hp + 1], pW1[4 * hp + 3]};
        Bbp[hp] = (f32x2){pb1[2 * hp],     pb1[2 * hp + 1]};
        Wop[hp] = (f32x2){pW2[2 * hp],     pW2[2 * hp + 1]};
    }
    float b2v = pb2[0];

    const unsigned short* qa_base = qaug + ((size_t)(b * N_ + qBase + wq) << 5) + kg * 8;
    const unsigned short* pa_base = paug + ((size_t)(b * N_ + pBase + wp) << 5) + kg * 8;

#pragma unroll
    for (int qt = 0; qt < 4; qt++) {
        f16x8 aaug = *(const f16x8*)(qa_base + ((qt * 16 + fr) << 5));
        int rowb = qBase + wq + qt * 16 + kg * 4;
#pragma unroll
        for (int pt = 0; pt < 4; pt++) {
            f16x8 baug = *(const f16x8*)(pa_base + ((pt * 16 + fr) << 5));
            f32x4 sacc = __builtin_amdgcn_mfma_f32_16x16x32_f16(
                aaug, baug, (f32x4){0.f, 0.f, 0.f, 0.f}, 0, 0, 0);
            f32x4 cval = acc[qt][pt];
            int col = pBase + wp + pt * 16 + fr;
#pragma unroll
            for (int r = 0; r < 4; r++) {
                float w1 = cval[r];
                float w2 = fminf(sacc[r], 0.f);   // = -max(d2, 0)
                f32x2 w1p = {w1, w1}, w2p = {w2, w2};
                f32x2 o = {b2v, 0.f};
#pragma unroll
                for (int hp = 0; hp < 8; hp++) {
                    f32x2 t = __builtin_elementwise_fma(w2p, Wbp[hp], Bbp[hp]);
                    t = __builtin_elementwise_fma(w1p, Wap[hp], t);
                    t = __builtin_elementwise_max(t, (f32x2){0.f, 0.f});
                    o = __builtin_elementwise_fma(t, Wop[hp], o);
                }
                w_out[((size_t)(b * N_ + rowb + r)) * N_ + col] = o.x + o.y;
            }
        }
    }
}

// ---------------------------------------------------------------------------
// Kernel 3: threshold candidate select -> exact fp64 rescore -> exact top-8
// via LDS rank -> softmax + gather + pool.  (unchanged from round 5)
// ---------------------------------------------------------------------------
__global__ __launch_bounds__(256)
void topk_kernel(const float* __restrict__ w, const float* __restrict__ f1,
                 const float* __restrict__ f2,
                 const float* __restrict__ pc, const float* __restrict__ qc,
                 const float* __restrict__ pW1, const float* __restrict__ pb1,
                 const float* __restrict__ pW2, const float* __restrict__ pb2,
                 const double* __restrict__ dinv1,
                 float* __restrict__ f_out, float* __restrict__ idx_out) {
    __shared__ int    s_cand[4][POOL];
    __shared__ double s_val[4][POOL];
    __shared__ int    s_idx[4][POOL];
    __shared__ double s_rv[4][K_];
    __shared__ int    s_ri[4][K_];

    int tid  = threadIdx.x;
    int wix  = tid >> 6;
    int lane = tid & 63;
    int row  = blockIdx.x * 4 + wix;          // grid is exact: row < B_*N_
    int b    = row >> 11;
    const float* wrow = w + (size_t)row * N_;

    // ---- phase 1: vector scan, per-lane max only ----
    float4 v4s[8];
    float mymax = -INFINITY;
#pragma unroll
    for (int j = 0; j < 8; j++) {
        v4s[j] = *(const float4*)(wrow + lane * 4 + j * 256);
        mymax = fmaxf(mymax,
                 fmaxf(fmaxf(v4s[j].x, v4s[j].y), fmaxf(v4s[j].z, v4s[j].w)));
    }

    // ---- phase 2a: T = PSEL-th largest of the 64 lane-maxes ----
    unsigned mk = ford(mymax);
    unsigned T = 0;
    for (int bit = 31; bit >= 0; --bit) {
        unsigned c = T | (1u << bit);
        if (__popcll(__ballot(mk >= c)) >= PSEL) T = c;
    }
    float Tf = unford(T);

    // ---- phase 2b: ballot prefix compaction of {v >= Tf} ----
    unsigned long long below = (1ull << lane) - 1ull;
    int total = 0;
#pragma unroll
    for (int j = 0; j < 8; j++) {
        float vv[4] = {v4s[j].x, v4s[j].y, v4s[j].z, v4s[j].w};
#pragma unroll
        for (int c = 0; c < 4; c++) {
            bool in = vv[c] >= Tf;
            unsigned long long m = __ballot(in);
            if (in) {
                int pos = total + __popcll(m & below);
                if (pos < POOL) s_cand[wix][pos] = lane * 4 + j * 256 + c;
            }
            total += __popcll(m);
        }
    }
    int ncand = total < POOL ? total : POOL;
    asm volatile("s_waitcnt lgkmcnt(0)" ::: "memory");   // in-wave LDS drain

    // ---- phase 3: parallel exact fp64 rescore (f1 norms precomputed) ----
    int sl = lane & 7;
    int gr = lane >> 3;
    const float* f2r = f2 + (size_t)row * D_ + sl * 32;
    float4 a4[8];
#pragma unroll
    for (int t = 0; t < 8; t++) a4[t] = *(const float4*)(f2r + t * 4);

    double daa = 0.0;
#pragma unroll
    for (int t = 0; t < 8; t++) {
        daa += (double)a4[t].x * (double)a4[t].x;
        daa += (double)a4[t].y * (double)a4[t].y;
        daa += (double)a4[t].z * (double)a4[t].z;
        daa += (double)a4[t].w * (double)a4[t].w;
    }
#pragma unroll
    for (int off = 1; off < 8; off <<= 1) daa += __shfl_xor(daa, off, 64);
    double inv_a = 1.0 / (sqrt(daa) + 1e-8);

    double mydab = 0.0;
    int myci = 0;
    int NR = (ncand + 7) >> 3;               // <= 8 rounds (wave-uniform)
    for (int r = 0; r < NR; r++) {
        int k = 8 * r + gr;
        int cj = (k < ncand) ? s_cand[wix][k] : 0;
        const float* f1r = f1 + ((size_t)(b * N_ + cj)) * D_ + sl * 32;
        double sA = 0.0;
#pragma unroll
        for (int t = 0; t < 8; t++) {
            float4 b4 = *(const float4*)(f1r + t * 4);
            sA += (double)a4[t].x * (double)b4.x;
            sA += (double)a4[t].y * (double)b4.y;
            sA += (double)a4[t].z * (double)b4.z;
            sA += (double)a4[t].w * (double)b4.w;
        }
#pragma unroll
        for (int off = 1; off < 8; off <<= 1) sA += __shfl_xor(sA, off, 64);
        if (sl == r) { mydab = sA; myci = cj; }
    }

    // lane (gr, sl) owns candidate k = 8*sl + gr
    int myk = 8 * sl + gr;
    double ex = -INFINITY;
    int    ei = 0x7fffffff;
    if (myk < ncand) {
        ei = myci;
        double w1d = mydab * inv_a * dinv1[b * N_ + myci];
        const float* qp = qc + (size_t)row * 3;
        double qx = qp[0], qy = qp[1], qz = qp[2];
        const float* pp = pc + ((size_t)(b * N_ + myci)) * 3;
        double px = pp[0], py = pp[1], pz = pp[2];
        double d2 = (qx * qx + qy * qy + qz * qz) + (px * px + py * py + pz * pz)
                  - 2.0 * (qx * px + qy * py + qz * pz);
        double w2d = -fmax(d2, 0.0);
        double out = (double)pb2[0];
#pragma unroll
        for (int h = 0; h < H_; h++) {
            double t = (double)pW1[2 * h] * w1d + (double)pW1[2 * h + 1] * w2d
                     + (double)pb1[h];
            out += (double)pW2[h] * fmax(t, 0.0);
        }
        ex = out;
    }

    // ---- phase 4: exact top-8 via LDS rank (desc, smaller idx tie) ----
    s_val[wix][myk] = ex;
    s_idx[wix][myk] = ei;
    asm volatile("s_waitcnt lgkmcnt(0)" ::: "memory");   // in-wave LDS drain
    {
        int rank = 0;
#pragma unroll
        for (int j = 0; j < POOL; j++) {
            double vj = s_val[wix][j];
            int    ij = s_idx[wix][j];
            rank += (vj > ex || (vj == ex && ij < ei)) ? 1 : 0;
        }
        if (rank < K_) { s_rv[wix][rank] = ex; s_ri[wix][rank] = ei; }
    }
    asm volatile("s_waitcnt lgkmcnt(0)" ::: "memory");   // in-wave LDS drain

    double outv[K_];
    int    outi[K_];
#pragma unroll
    for (int r = 0; r < K_; r++) { outv[r] = s_rv[wix][r]; outi[r] = s_ri[wix][r]; }

    // ---- phase 5: softmax + gather + pool + write ----
    float m = (float)outv[0];
    float e[K_], s = 0.f;
#pragma unroll
    for (int r = 0; r < K_; r++) { e[r] = expf((float)outv[r] - m); s += e[r]; }
    float inv_s = 1.f / s;

    const float* f1b = f1 + ((size_t)b * N_) * D_;
    size_t obase = (size_t)row * (2 * D_);
#pragma unroll
    for (int jd = 0; jd < D_ / 64; jd++) {
        int d = lane + 64 * jd;
        float accv = 0.f, mx = -INFINITY;
#pragma unroll
        for (int r = 0; r < K_; r++) {
            float x = f1b[(size_t)outi[r] * D_ + d];
            accv += (e[r] * inv_s) * x;
            mx = fmaxf(mx, x);
        }
        f_out[obase + d]      = accv;
        f_out[obase + D_ + d] = mx;
    }
    if (lane == 0) {
#pragma unroll
        for (int r = 0; r < K_; r++) idx_out[(size_t)row * K_ + r] = (float)outi[r];
    }
}

// ---------------------------------------------------------------------------
extern "C" void kernel_launch(void* const* d_in, const int* in_sizes, int n_in,
                              void* d_out, int out_size, void* d_ws, size_t ws_size,
                              hipStream_t stream) {
    const float* f1 = (const float*)d_in[0];
    const float* f2 = (const float*)d_in[1];
    const float* pc = (const float*)d_in[2];
    const float* qc = (const float*)d_in[3];
    const float* W1 = (const float*)d_in[4];
    const float* b1 = (const float*)d_in[5];
    const float* W2 = (const float*)d_in[6];
    const float* b2 = (const float*)d_in[7];

    float* out     = (float*)d_out;
    float* f_out   = out;                                   // [B,N,2D]
    float* idx_out = f_out + (size_t)B_ * N_ * 2 * D_;      // [B,N,K] as float
    float* w_out   = idx_out + (size_t)B_ * N_ * K_;        // [B,N,N]

    // Scratch in the f_out region (33,554,432 B): 3 fp16 panels (25.2 MB) +
    // 2 augmented coord arrays (2 x 1 MB).  f_out is only written by
    // topk_kernel afterwards, so this is safe under stream ordering.
    unsigned short* s1h  = (unsigned short*)f_out;          // f1 hi (B side)
    unsigned short* s1l  = s1h + (size_t)B_ * N_ * D_;      // f1 lo (B side)
    unsigned short* s2h  = s1l + (size_t)B_ * N_ * D_;      // f2 hi (A side)
    unsigned short* qaug = s2h + (size_t)B_ * N_ * D_;      // [B*N][32] fp16
    unsigned short* paug = qaug + (size_t)B_ * N_ * 32;     // [B*N][32] fp16

    // fp64 f1 inverse norms in d_ws: B*N doubles = 131072 B
    double* dinv1 = (double*)d_ws;

    prep_kernel<<<(2 * B_ * N_) / 4, 256, 0, stream>>>(f1, f2, pc, qc,
                                                       s1h, s1l, s2h,
                                                       qaug, paug, dinv1);

    dim3 g2(N_ / BM, N_ / BM, B_);
    gemm_mlp_kernel<<<g2, 256, 0, stream>>>(s2h, s1h, s1l, qaug, paug,
                                            W1, b1, W2, b2, w_out);

    topk_kernel<<<(B_ * N_) / 4, 256, 0, stream>>>(w_out, f1, f2, pc, qc,
                                                   W1, b1, W2, b2, dinv1,
                                                   f_out, idx_out);
}

// Round 7
// 343.937 us; speedup vs baseline: 3.6002x; 1.1019x over previous
//
#include <hip/hip_runtime.h>
#include <math.h>

// Problem constants (fixed by setup_inputs)
constexpr int B_ = 8;
constexpr int N_ = 2048;
constexpr int D_ = 256;
constexpr int H_ = 16;
constexpr int K_ = 8;
constexpr int POOL = 64;   // candidate pool capacity (threshold select)
constexpr int PSEL = 16;   // select T = PSEL-th largest lane-max (pool >= PSEL)

constexpr int BM = 128;    // tile rows (q and p)
constexpr int BK = 32;     // k chunk per stage (1 MFMA K-step), double-buffered

typedef _Float16 f16x8 __attribute__((ext_vector_type(8)));
typedef float    f32x4 __attribute__((ext_vector_type(4)));
typedef float    f32x2 __attribute__((ext_vector_type(2)));

// address-space-qualified pointers for global_load_lds
typedef __attribute__((address_space(3))) unsigned int       lds_u32_t;
typedef __attribute__((address_space(1))) const unsigned int glb_u32_t;

__device__ __forceinline__ void g2l16(const void* g, void* l) {
    // 16B direct global->LDS (dest = wave-uniform base + lane*16)
    __builtin_amdgcn_global_load_lds((glb_u32_t*)g, (lds_u32_t*)l, 16, 0, 0);
}

// order-preserving float -> uint map: a > b  <=>  ford(a) > ford(b)
__device__ __forceinline__ unsigned ford(float f) {
    unsigned u = __float_as_uint(f);
    return (u & 0x80000000u) ? ~u : (u | 0x80000000u);
}
__device__ __forceinline__ float unford(unsigned t) {
    return (t & 0x80000000u) ? __uint_as_float(t & 0x7FFFFFFFu)
                             : __uint_as_float(~t);
}

__device__ __forceinline__ unsigned pk16(_Float16 a, _Float16 b) {
    unsigned short ua = __builtin_bit_cast(unsigned short, a);
    unsigned short ub = __builtin_bit_cast(unsigned short, b);
    return (unsigned)ua | ((unsigned)ub << 16);
}

// fp32*scale -> fp16 hi (RNE) + fp16 lo (RNE residual), packed pairs
__device__ inline void split4_f16(float4 v, float s, uint2& hi, uint2& lo) {
    float a = v.x * s, b = v.y * s, c = v.z * s, d = v.w * s;
    _Float16 ha = (_Float16)a, hb = (_Float16)b;
    _Float16 hc = (_Float16)c, hd = (_Float16)d;
    _Float16 la = (_Float16)(a - (float)ha), lb = (_Float16)(b - (float)hb);
    _Float16 lc = (_Float16)(c - (float)hc), ld = (_Float16)(d - (float)hd);
    hi.x = pk16(ha, hb); hi.y = pk16(hc, hd);
    lo.x = pk16(la, lb); lo.y = pk16(lc, ld);
}

// ---------------------------------------------------------------------------
// Kernel 1 (prep): fp32 -> normalized fp16 split (tile-panel-major, swizzled
// for linear global_load_lds) + fp64 inverse norms for BOTH f1 (dinv1) and
// f2 (dinv2, if workspace allows) + fp16 hi/lo AUGMENTED coordinate rows:
//   dot(qaug,paug) = 2q.p - |q|2 - |p|2 = -d2   (err ~1e-6)
// ---------------------------------------------------------------------------
__global__ __launch_bounds__(256)
void prep_kernel(const float* __restrict__ f1, const float* __restrict__ f2,
                 const float* __restrict__ pcoord, const float* __restrict__ qcoord,
                 unsigned short* __restrict__ s1h, unsigned short* __restrict__ s1l,
                 unsigned short* __restrict__ s2h,
                 unsigned short* __restrict__ qaug, unsigned short* __restrict__ paug,
                 double* __restrict__ dinv1, double* __restrict__ dinv2) {
    int gid  = blockIdx.x * blockDim.x + threadIdx.x;
    int wave = gid >> 6;
    int lane = gid & 63;
    if (wave >= 2 * B_ * N_) return;
    bool is1 = wave < B_ * N_;
    int r = is1 ? wave : wave - B_ * N_;

    const float* src = (is1 ? f1 : f2) + (size_t)r * D_;
    float4 v = *(const float4*)(src + lane * 4);
    float ss = v.x * v.x + v.y * v.y + v.z * v.z + v.w * v.w;
#pragma unroll
    for (int off = 32; off > 0; off >>= 1) ss += __shfl_xor(ss, off, 64);
    float inv = 1.0f / (sqrtf(ss) + 1e-8f);

    uint2 hi, lo;
    split4_f16(v, inv, hi, lo);

    int panel = r >> 7, rloc = r & 127;
    int s     = lane >> 1;                   // 16B slot index 0..31 (256 elems)
    int chunk = s >> 2;                      // which 32-elem k-chunk (tile) 0..7
    int sl    = (s & 3) ^ ((rloc >> 1) & 3); // swizzled slot within 64B row
    int half  = lane & 1;
    size_t idx = ((size_t)(panel * 8 + chunk) << 12)   // tile * 4096 ushorts
               + (size_t)rloc * 32 + sl * 8 + half * 4;

    // exact fp64 inverse norm (hoisted out of topk's rescore)
    bool wantd = is1 || (dinv2 != nullptr);
    if (wantd) {
        double dss = (double)v.x * v.x + (double)v.y * v.y
                   + (double)v.z * v.z + (double)v.w * v.w;
#pragma unroll
        for (int off = 32; off > 0; off >>= 1) dss += __shfl_xor(dss, off, 64);
        if (lane == 0) {
            double dv = 1.0 / (sqrt(dss) + 1e-8);
            if (is1) dinv1[r] = dv; else dinv2[r] = dv;
        }
    }

    if (is1) {
        *(uint2*)&s1h[idx] = hi;
        *(uint2*)&s1l[idx] = lo;
    } else {
        *(uint2*)&s2h[idx] = hi;
    }

    // augmented coord row (lane 0, scalar; tiny)
    if (lane == 0) {
        const float* cp = (is1 ? pcoord : qcoord) + (size_t)r * 3;
        float x = cp[0], y = cp[1], z = cp[2];
        const float s2 = 1.41421356237309515f;
        _Float16 xh = (_Float16)(s2 * x), yh = (_Float16)(s2 * y), zh = (_Float16)(s2 * z);
        _Float16 xl = (_Float16)(s2 * x - (float)xh);
        _Float16 yl = (_Float16)(s2 * y - (float)yh);
        _Float16 zl = (_Float16)(s2 * z - (float)zh);
        float nn = x * x + y * y + z * z;
        _Float16 nh = (_Float16)nn, nl = (_Float16)(nn - (float)nh);
        _Float16 one = (_Float16)1.0f;
        _Float16 mnh = -nh, mnl = -nl;
        unsigned short h[32];
#pragma unroll
        for (int i = 0; i < 32; i++) h[i] = 0;
#define US_(v) __builtin_bit_cast(unsigned short, v)
        if (is1) {   // p side
            h[0] = US_(xh); h[1] = US_(yh); h[2] = US_(zh);
            h[3] = US_(xh); h[4] = US_(yh); h[5] = US_(zh);
            h[6] = US_(xl); h[7] = US_(yl); h[8] = US_(zl);
            h[9] = US_(one); h[10] = US_(one);
            h[11] = US_(mnh); h[12] = US_(mnl);
        } else {     // q side
            h[0] = US_(xh); h[1] = US_(yh); h[2] = US_(zh);
            h[3] = US_(xl); h[4] = US_(yl); h[5] = US_(zl);
            h[6] = US_(xh); h[7] = US_(yh); h[8] = US_(zh);
            h[9] = US_(mnh); h[10] = US_(mnl);
            h[11] = US_(one); h[12] = US_(one);
        }
#undef US_
        unsigned short* dst = (is1 ? paug : qaug) + (size_t)r * 32;
#pragma unroll
        for (int i = 0; i < 4; i++) ((uint4*)dst)[i] = ((const uint4*)h)[i];
    }
}

// ---------------------------------------------------------------------------
// Kernel 2: MFMA cosine-sim GEMM (asymmetric fp16 2-term: hA*(hB+lB)) +
// w2 via augmented-coord MFMA + h-paired pk-f32 MLP.  BK=32 double-buffered,
// 2-phase prefetch.  (unchanged from round 6 — verified)
// ---------------------------------------------------------------------------
__global__ __launch_bounds__(256, 3)
void gemm_mlp_kernel(const unsigned short* __restrict__ aH0,  // f2 hi (A, q)
                     const unsigned short* __restrict__ bH0,  // f1 hi (B, p)
                     const unsigned short* __restrict__ bL0,  // f1 lo (B, p)
                     const unsigned short* __restrict__ qaug,
                     const unsigned short* __restrict__ paug,
                     const float* __restrict__ pW1, const float* __restrict__ pb1,
                     const float* __restrict__ pW2, const float* __restrict__ pb2,
                     float* __restrict__ w_out) {
    // 2 buffers x 3 tiles (Ahi | Bhi | Blo) x 8 KiB = 48 KiB
    __shared__ unsigned short ldsbuf[2 * 3 * 4096];

    int tid = threadIdx.x;
    // bijective XCD chunking swizzle within each z-slice (256 blocks, 256%8==0)
    int l  = blockIdx.x + (blockIdx.y << 4);
    int ls = ((l & 7) << 5) | (l >> 3);
    int pBase = (ls & 15) * BM;
    int qBase = (ls >> 4) * BM;
    int b = blockIdx.z;

    int lane = tid & 63;
    int wv   = tid >> 6;
    int wq = (wv >> 1) * 64;
    int wp = (wv & 1) * 64;
    int fr = lane & 15;
    int kg = lane >> 4;

    const int Apanel8 = ((b * N_ + qBase) >> 7) * 8;   // 8 KiB tile idx base
    const int Bpanel8 = ((b * N_ + pBase) >> 7) * 8;

    char* ldsB = (char*)&ldsbuf[0];
    const int wlo = (wv << 11) + (lane << 4);   // per-lane global byte offset
    const int wdo = (wv << 11);                 // wave-uniform LDS byte offset
    const int cw  = (kg ^ ((fr >> 1) & 3)) << 4;  // swizzled 16B slot

    f32x4 acc[4][4] = {};

#define STAGE(buf, c)                                                          \
    {                                                                          \
        const char* aH = (const char*)aH0 + ((size_t)(Apanel8 + (c)) << 13);   \
        const char* bH = (const char*)bH0 + ((size_t)(Bpanel8 + (c)) << 13);   \
        const char* bL = (const char*)bL0 + ((size_t)(Bpanel8 + (c)) << 13);   \
        char* dst = ldsB + (buf) * 24576;                                      \
        _Pragma("unroll")                                                      \
        for (int i = 0; i < 2; i++) {                                          \
            int o = i << 10;                                                   \
            g2l16(aH + wlo + o, dst + 0     + wdo + o);                        \
            g2l16(bH + wlo + o, dst + 8192  + wdo + o);                        \
            g2l16(bL + wlo + o, dst + 16384 + wdo + o);                        \
        }                                                                      \
    }

    STAGE(0, 0);
    __syncthreads();                       // drain: buf0 ready

#pragma unroll
    for (int c = 0; c < 8; c++) {          // 8 K-chunks of 32
        if (c < 7) STAGE((c + 1) & 1, c + 1);   // prefetch next (other buffer)

        char* base = ldsB + (c & 1) * 24576;
        f16x8 ah[4], bh[4], bl[4];
#pragma unroll
        for (int t = 0; t < 4; t++) {
            int ra = (wq + t * 16 + fr) * 64;
            int rb = (wp + t * 16 + fr) * 64;
            ah[t] = *(const f16x8*)(base + 0     + ra + cw);
            bh[t] = *(const f16x8*)(base + 8192  + rb + cw);
            bl[t] = *(const f16x8*)(base + 16384 + rb + cw);
        }
#pragma unroll
        for (int qt = 0; qt < 4; qt++) {
#pragma unroll
            for (int pt = 0; pt < 4; pt++) {
                acc[qt][pt] = __builtin_amdgcn_mfma_f32_16x16x32_f16(
                    ah[qt], bh[pt], acc[qt][pt], 0, 0, 0);
                acc[qt][pt] = __builtin_amdgcn_mfma_f32_16x16x32_f16(
                    ah[qt], bl[pt], acc[qt][pt], 0, 0, 0);
            }
        }
        __syncthreads();   // drains prefetch vmcnt + all waves done with buf
    }
#undef STAGE

    // ---------------- epilogue: w2 MFMA + h-paired MLP + store -------------
    f32x2 Wap[8], Wbp[8], Bbp[8], Wop[8];
#pragma unroll
    for (int hp = 0; hp < 8; hp++) {
        Wap[hp] = (f32x2){pW1[4 * hp],     pW1[4 * hp + 2]};
        Wbp[hp] = (f32x2){pW1[4 * hp + 1], pW1[4 * hp + 3]};
        Bbp[hp] = (f32x2){pb1[2 * hp],     pb1[2 * hp + 1]};
        Wop[hp] = (f32x2){pW2[2 * hp],     pW2[2 * hp + 1]};
    }
    float b2v = pb2[0];

    const unsigned short* qa_base = qaug + ((size_t)(b * N_ + qBase + wq) << 5) + kg * 8;
    const unsigned short* pa_base = paug + ((size_t)(b * N_ + pBase + wp) << 5) + kg * 8;

#pragma unroll
    for (int qt = 0; qt < 4; qt++) {
        f16x8 aaug = *(const f16x8*)(qa_base + ((qt * 16 + fr) << 5));
        int rowb = qBase + wq + qt * 16 + kg * 4;
#pragma unroll
        for (int pt = 0; pt < 4; pt++) {
            f16x8 baug = *(const f16x8*)(pa_base + ((pt * 16 + fr) << 5));
            f32x4 sacc = __builtin_amdgcn_mfma_f32_16x16x32_f16(
                aaug, baug, (f32x4){0.f, 0.f, 0.f, 0.f}, 0, 0, 0);
            f32x4 cval = acc[qt][pt];
            int col = pBase + wp + pt * 16 + fr;
#pragma unroll
            for (int r = 0; r < 4; r++) {
                float w1 = cval[r];
                float w2 = fminf(sacc[r], 0.f);   // = -max(d2, 0)
                f32x2 w1p = {w1, w1}, w2p = {w2, w2};
                f32x2 o = {b2v, 0.f};
#pragma unroll
                for (int hp = 0; hp < 8; hp++) {
                    f32x2 t = __builtin_elementwise_fma(w2p, Wbp[hp], Bbp[hp]);
                    t = __builtin_elementwise_fma(w1p, Wap[hp], t);
                    t = __builtin_elementwise_max(t, (f32x2){0.f, 0.f});
                    o = __builtin_elementwise_fma(t, Wop[hp], o);
                }
                w_out[((size_t)(b * N_ + rowb + r)) * N_ + col] = o.x + o.y;
            }
        }
    }
}

// ---------------------------------------------------------------------------
// Kernel 3: threshold candidate select -> exact fp64 rescore (ILP partial
// sums, precomputed norms both sides) -> exact top-8 via LDS rank (bounded
// by ncand) -> softmax + gather + pool.  One wave per (b,q) row.
// ---------------------------------------------------------------------------
__global__ __launch_bounds__(256)
void topk_kernel(const float* __restrict__ w, const float* __restrict__ f1,
                 const float* __restrict__ f2,
                 const float* __restrict__ pc, const float* __restrict__ qc,
                 const float* __restrict__ pW1, const float* __restrict__ pb1,
                 const float* __restrict__ pW2, const float* __restrict__ pb2,
                 const double* __restrict__ dinv1, const double* __restrict__ dinv2,
                 float* __restrict__ f_out, float* __restrict__ idx_out) {
    __shared__ int    s_cand[4][POOL];
    __shared__ double s_val[4][POOL];
    __shared__ int    s_idx[4][POOL];
    __shared__ double s_rv[4][K_];
    __shared__ int    s_ri[4][K_];

    int tid  = threadIdx.x;
    int wix  = tid >> 6;
    int lane = tid & 63;
    int row  = blockIdx.x * 4 + wix;          // grid is exact: row < B_*N_
    int b    = row >> 11;
    const float* wrow = w + (size_t)row * N_;

    // ---- phase 1: vector scan, per-lane max only ----
    float4 v4s[8];
    float mymax = -INFINITY;
#pragma unroll
    for (int j = 0; j < 8; j++) {
        v4s[j] = *(const float4*)(wrow + lane * 4 + j * 256);
        mymax = fmaxf(mymax,
                 fmaxf(fmaxf(v4s[j].x, v4s[j].y), fmaxf(v4s[j].z, v4s[j].w)));
    }

    // ---- phase 2a: T = PSEL-th largest of the 64 lane-maxes ----
    unsigned mk = ford(mymax);
    unsigned T = 0;
    for (int bit = 31; bit >= 0; --bit) {
        unsigned c = T | (1u << bit);
        if (__popcll(__ballot(mk >= c)) >= PSEL) T = c;
    }
    float Tf = unford(T);

    // ---- phase 2b: ballot prefix compaction of {v >= Tf} ----
    unsigned long long below = (1ull << lane) - 1ull;
    int total = 0;
#pragma unroll
    for (int j = 0; j < 8; j++) {
        float vv[4] = {v4s[j].x, v4s[j].y, v4s[j].z, v4s[j].w};
#pragma unroll
        for (int c = 0; c < 4; c++) {
            bool in = vv[c] >= Tf;
            unsigned long long m = __ballot(in);
            if (in) {
                int pos = total + __popcll(m & below);
                if (pos < POOL) s_cand[wix][pos] = lane * 4 + j * 256 + c;
            }
            total += __popcll(m);
        }
    }
    int ncand = total < POOL ? total : POOL;   // always >= PSEL = 16 > K_
    asm volatile("s_waitcnt lgkmcnt(0)" ::: "memory");   // in-wave LDS drain

    // ---- phase 3: parallel exact fp64 rescore (norms precomputed) ----
    int sl = lane & 7;
    int gr = lane >> 3;
    const float* f2r = f2 + ((size_t)row << 8) + sl * 32;
    float4 a4[8];
#pragma unroll
    for (int t = 0; t < 8; t++) a4[t] = *(const float4*)(f2r + t * 4);

    double inv_a;
    if (dinv2) {
        inv_a = dinv2[row];
    } else {
        double daa = 0.0;
#pragma unroll
        for (int t = 0; t < 8; t++) {
            daa += (double)a4[t].x * (double)a4[t].x;
            daa += (double)a4[t].y * (double)a4[t].y;
            daa += (double)a4[t].z * (double)a4[t].z;
            daa += (double)a4[t].w * (double)a4[t].w;
        }
#pragma unroll
        for (int off = 1; off < 8; off <<= 1) daa += __shfl_xor(daa, off, 64);
        inv_a = 1.0 / (sqrt(daa) + 1e-8);
    }

    const float* f1bb = f1 + ((size_t)(b * N_) << 8);
    double mydab = 0.0;
    int myci = 0;
    int NR = (ncand + 7) >> 3;               // typically 3 (wave-uniform)
    for (int r = 0; r < NR; r++) {
        int k = 8 * r + gr;
        int cj = (k < ncand) ? s_cand[wix][k] : 0;
        const float* f1r = f1bb + ((unsigned)(cj << 8)) + sl * 32;
        double ps0 = 0.0, ps1 = 0.0, ps2 = 0.0, ps3 = 0.0;   // 4-way ILP
#pragma unroll
        for (int t = 0; t < 8; t += 4) {
            float4 b0 = *(const float4*)(f1r + t * 4);
            float4 b1 = *(const float4*)(f1r + t * 4 + 4);
            float4 b2 = *(const float4*)(f1r + t * 4 + 8);
            float4 b3 = *(const float4*)(f1r + t * 4 + 12);
            ps0 += (double)a4[t].x * b0.x + (double)a4[t].y * b0.y
                 + (double)a4[t].z * b0.z + (double)a4[t].w * b0.w;
            ps1 += (double)a4[t+1].x * b1.x + (double)a4[t+1].y * b1.y
                 + (double)a4[t+1].z * b1.z + (double)a4[t+1].w * b1.w;
            ps2 += (double)a4[t+2].x * b2.x + (double)a4[t+2].y * b2.y
                 + (double)a4[t+2].z * b2.z + (double)a4[t+2].w * b2.w;
            ps3 += (double)a4[t+3].x * b3.x + (double)a4[t+3].y * b3.y
                 + (double)a4[t+3].z * b3.z + (double)a4[t+3].w * b3.w;
        }
        double sA = (ps0 + ps1) + (ps2 + ps3);
#pragma unroll
        for (int off = 1; off < 8; off <<= 1) sA += __shfl_xor(sA, off, 64);
        if (sl == r) { mydab = sA; myci = cj; }
    }

    // lane (gr, sl) owns candidate k = 8*sl + gr
    int myk = 8 * sl + gr;
    double ex = -INFINITY;
    int    ei = 0x7fffffff;
    if (myk < ncand) {
        ei = myci;
        double w1d = mydab * inv_a * dinv1[b * N_ + myci];
        const float* qp = qc + (size_t)row * 3;
        double qx = qp[0], qy = qp[1], qz = qp[2];
        const float* pp = pc + ((size_t)(b * N_ + myci)) * 3;
        double px = pp[0], py = pp[1], pz = pp[2];
        double d2 = (qx * qx + qy * qy + qz * qz) + (px * px + py * py + pz * pz)
                  - 2.0 * (qx * px + qy * py + qz * pz);
        double w2d = -fmax(d2, 0.0);
        double out = (double)pb2[0];
#pragma unroll
        for (int h = 0; h < H_; h++) {
            double t = (double)pW1[2 * h] * w1d + (double)pW1[2 * h + 1] * w2d
                     + (double)pb1[h];
            out += (double)pW2[h] * fmax(t, 0.0);
        }
        ex = out;
    }

    // ---- phase 4: exact top-8 via LDS rank (desc, smaller idx tie) ----
    // all 64 slots written (myk covers 0..63); slots >= ncand hold -INF and
    // can never outrank, so the rank loop is bounded by ncand.
    s_val[wix][myk] = ex;
    s_idx[wix][myk] = ei;
    asm volatile("s_waitcnt lgkmcnt(0)" ::: "memory");   // in-wave LDS drain
    {
        int rank = 0;
        for (int j = 0; j < ncand; j++) {
            double vj = s_val[wix][j];
            int    ij = s_idx[wix][j];
            rank += (vj > ex || (vj == ex && ij < ei)) ? 1 : 0;
        }
        if (rank < K_ && myk < ncand) { s_rv[wix][rank] = ex; s_ri[wix][rank] = ei; }
    }
    asm volatile("s_waitcnt lgkmcnt(0)" ::: "memory");   // in-wave LDS drain

    double outv[K_];
    int    outi[K_];
#pragma unroll
    for (int r = 0; r < K_; r++) { outv[r] = s_rv[wix][r]; outi[r] = s_ri[wix][r]; }

    // ---- phase 5: softmax + gather + pool + write ----
    float m = (float)outv[0];
    float e[K_], s = 0.f;
#pragma unroll
    for (int r = 0; r < K_; r++) { e[r] = expf((float)outv[r] - m); s += e[r]; }
    float inv_s = 1.f / s;

    const float* f1b = f1 + ((size_t)b * N_) * D_;
    size_t obase = (size_t)row * (2 * D_);
#pragma unroll
    for (int jd = 0; jd < D_ / 64; jd++) {
        int d = lane + 64 * jd;
        float accv = 0.f, mx = -INFINITY;
#pragma unroll
        for (int r = 0; r < K_; r++) {
            float x = f1b[(size_t)outi[r] * D_ + d];
            accv += (e[r] * inv_s) * x;
            mx = fmaxf(mx, x);
        }
        f_out[obase + d]      = accv;
        f_out[obase + D_ + d] = mx;
    }
    if (lane == 0) {
#pragma unroll
        for (int r = 0; r < K_; r++) idx_out[(size_t)row * K_ + r] = (float)outi[r];
    }
}

// ---------------------------------------------------------------------------
extern "C" void kernel_launch(void* const* d_in, const int* in_sizes, int n_in,
                              void* d_out, int out_size, void* d_ws, size_t ws_size,
                              hipStream_t stream) {
    const float* f1 = (const float*)d_in[0];
    const float* f2 = (const float*)d_in[1];
    const float* pc = (const float*)d_in[2];
    const float* qc = (const float*)d_in[3];
    const float* W1 = (const float*)d_in[4];
    const float* b1 = (const float*)d_in[5];
    const float* W2 = (const float*)d_in[6];
    const float* b2 = (const float*)d_in[7];

    float* out     = (float*)d_out;
    float* f_out   = out;                                   // [B,N,2D]
    float* idx_out = f_out + (size_t)B_ * N_ * 2 * D_;      // [B,N,K] as float
    float* w_out   = idx_out + (size_t)B_ * N_ * K_;        // [B,N,N]

    // Scratch in the f_out region (33,554,432 B): 3 fp16 panels (25.2 MB) +
    // 2 augmented coord arrays (2 x 1 MB).  f_out is only written by
    // topk_kernel afterwards, so this is safe under stream ordering.
    unsigned short* s1h  = (unsigned short*)f_out;          // f1 hi (B side)
    unsigned short* s1l  = s1h + (size_t)B_ * N_ * D_;      // f1 lo (B side)
    unsigned short* s2h  = s1l + (size_t)B_ * N_ * D_;      // f2 hi (A side)
    unsigned short* qaug = s2h + (size_t)B_ * N_ * D_;      // [B*N][32] fp16
    unsigned short* paug = qaug + (size_t)B_ * N_ * 32;     // [B*N][32] fp16

    // fp64 inverse norms in d_ws: dinv1 always (128 KiB); dinv2 only if the
    // workspace is large enough (topk has an exact in-kernel fallback).
    double* dinv1 = (double*)d_ws;
    double* dinv2 = (ws_size >= (size_t)2 * B_ * N_ * sizeof(double))
                  ? dinv1 + (size_t)B_ * N_ : nullptr;

    prep_kernel<<<(2 * B_ * N_) / 4, 256, 0, stream>>>(f1, f2, pc, qc,
                                                       s1h, s1l, s2h,
                                                       qaug, paug, dinv1, dinv2);

    dim3 g2(N_ / BM, N_ / BM, B_);
    gemm_mlp_kernel<<<g2, 256, 0, stream>>>(s2h, s1h, s1l, qaug, paug,
                                            W1, b1, W2, b2, w_out);

    topk_kernel<<<(B_ * N_) / 4, 256, 0, stream>>>(w_out, f1, f2, pc, qc,
                                                   W1, b1, W2, b2, dinv1, dinv2,
                                                   f_out, idx_out);
}

// Round 8
// 337.307 us; speedup vs baseline: 3.6709x; 1.0197x over previous
//
#include <hip/hip_runtime.h>
#include <math.h>

// Problem constants (fixed by setup_inputs)
constexpr int B_ = 8;
constexpr int N_ = 2048;
constexpr int D_ = 256;
constexpr int H_ = 16;
constexpr int K_ = 8;
constexpr int POOL = 64;   // candidate pool capacity (threshold select)
constexpr int PSEL = 16;   // select T = PSEL-th largest lane-max (pool >= PSEL)

constexpr int BM = 128;    // tile rows (q and p)
constexpr int BK = 32;     // k chunk per stage (1 MFMA K-step), double-buffered

typedef _Float16 f16x8 __attribute__((ext_vector_type(8)));
typedef float    f32x4 __attribute__((ext_vector_type(4)));
typedef float    f32x2 __attribute__((ext_vector_type(2)));

// address-space-qualified pointers for global_load_lds
typedef __attribute__((address_space(3))) unsigned int       lds_u32_t;
typedef __attribute__((address_space(1))) const unsigned int glb_u32_t;

__device__ __forceinline__ void g2l16(const void* g, void* l) {
    // 16B direct global->LDS (dest = wave-uniform base + lane*16)
    __builtin_amdgcn_global_load_lds((glb_u32_t*)g, (lds_u32_t*)l, 16, 0, 0);
}

// order-preserving float -> uint map: a > b  <=>  ford(a) > ford(b)
__device__ __forceinline__ unsigned ford(float f) {
    unsigned u = __float_as_uint(f);
    return (u & 0x80000000u) ? ~u : (u | 0x80000000u);
}
__device__ __forceinline__ float unford(unsigned t) {
    return (t & 0x80000000u) ? __uint_as_float(t & 0x7FFFFFFFu)
                             : __uint_as_float(~t);
}

__device__ __forceinline__ unsigned pk16(_Float16 a, _Float16 b) {
    unsigned short ua = __builtin_bit_cast(unsigned short, a);
    unsigned short ub = __builtin_bit_cast(unsigned short, b);
    return (unsigned)ua | ((unsigned)ub << 16);
}

// fp32*scale -> fp16 hi (RNE) + fp16 lo (RNE residual), packed pairs
__device__ inline void split4_f16(float4 v, float s, uint2& hi, uint2& lo) {
    float a = v.x * s, b = v.y * s, c = v.z * s, d = v.w * s;
    _Float16 ha = (_Float16)a, hb = (_Float16)b;
    _Float16 hc = (_Float16)c, hd = (_Float16)d;
    _Float16 la = (_Float16)(a - (float)ha), lb = (_Float16)(b - (float)hb);
    _Float16 lc = (_Float16)(c - (float)hc), ld = (_Float16)(d - (float)hd);
    hi.x = pk16(ha, hb); hi.y = pk16(hc, hd);
    lo.x = pk16(la, lb); lo.y = pk16(lc, ld);
}

// ---------------------------------------------------------------------------
// Kernel 1 (prep): fp32 -> normalized fp16 split (tile-panel-major, swizzled
// for linear global_load_lds) + fp64 inverse norms for BOTH f1 (dinv1) and
// f2 (dinv2, if workspace allows) + fp16 hi/lo AUGMENTED coordinate rows:
//   dot(qaug,paug) = 2q.p - |q|2 - |p|2 = -d2   (err ~1e-6)
// (unchanged from round 7 — verified)
// ---------------------------------------------------------------------------
__global__ __launch_bounds__(256)
void prep_kernel(const float* __restrict__ f1, const float* __restrict__ f2,
                 const float* __restrict__ pcoord, const float* __restrict__ qcoord,
                 unsigned short* __restrict__ s1h, unsigned short* __restrict__ s1l,
                 unsigned short* __restrict__ s2h,
                 unsigned short* __restrict__ qaug, unsigned short* __restrict__ paug,
                 double* __restrict__ dinv1, double* __restrict__ dinv2) {
    int gid  = blockIdx.x * blockDim.x + threadIdx.x;
    int wave = gid >> 6;
    int lane = gid & 63;
    if (wave >= 2 * B_ * N_) return;
    bool is1 = wave < B_ * N_;
    int r = is1 ? wave : wave - B_ * N_;

    const float* src = (is1 ? f1 : f2) + (size_t)r * D_;
    float4 v = *(const float4*)(src + lane * 4);
    float ss = v.x * v.x + v.y * v.y + v.z * v.z + v.w * v.w;
#pragma unroll
    for (int off = 32; off > 0; off >>= 1) ss += __shfl_xor(ss, off, 64);
    float inv = 1.0f / (sqrtf(ss) + 1e-8f);

    uint2 hi, lo;
    split4_f16(v, inv, hi, lo);

    int panel = r >> 7, rloc = r & 127;
    int s     = lane >> 1;                   // 16B slot index 0..31 (256 elems)
    int chunk = s >> 2;                      // which 32-elem k-chunk (tile) 0..7
    int sl    = (s & 3) ^ ((rloc >> 1) & 3); // swizzled slot within 64B row
    int half  = lane & 1;
    size_t idx = ((size_t)(panel * 8 + chunk) << 12)   // tile * 4096 ushorts
               + (size_t)rloc * 32 + sl * 8 + half * 4;

    // exact fp64 inverse norm (hoisted out of topk's rescore)
    bool wantd = is1 || (dinv2 != nullptr);
    if (wantd) {
        double dss = (double)v.x * v.x + (double)v.y * v.y
                   + (double)v.z * v.z + (double)v.w * v.w;
#pragma unroll
        for (int off = 32; off > 0; off >>= 1) dss += __shfl_xor(dss, off, 64);
        if (lane == 0) {
            double dv = 1.0 / (sqrt(dss) + 1e-8);
            if (is1) dinv1[r] = dv; else dinv2[r] = dv;
        }
    }

    if (is1) {
        *(uint2*)&s1h[idx] = hi;
        *(uint2*)&s1l[idx] = lo;
    } else {
        *(uint2*)&s2h[idx] = hi;
    }

    // augmented coord row (lane 0, scalar; tiny)
    if (lane == 0) {
        const float* cp = (is1 ? pcoord : qcoord) + (size_t)r * 3;
        float x = cp[0], y = cp[1], z = cp[2];
        const float s2 = 1.41421356237309515f;
        _Float16 xh = (_Float16)(s2 * x), yh = (_Float16)(s2 * y), zh = (_Float16)(s2 * z);
        _Float16 xl = (_Float16)(s2 * x - (float)xh);
        _Float16 yl = (_Float16)(s2 * y - (float)yh);
        _Float16 zl = (_Float16)(s2 * z - (float)zh);
        float nn = x * x + y * y + z * z;
        _Float16 nh = (_Float16)nn, nl = (_Float16)(nn - (float)nh);
        _Float16 one = (_Float16)1.0f;
        _Float16 mnh = -nh, mnl = -nl;
        unsigned short h[32];
#pragma unroll
        for (int i = 0; i < 32; i++) h[i] = 0;
#define US_(v) __builtin_bit_cast(unsigned short, v)
        if (is1) {   // p side
            h[0] = US_(xh); h[1] = US_(yh); h[2] = US_(zh);
            h[3] = US_(xh); h[4] = US_(yh); h[5] = US_(zh);
            h[6] = US_(xl); h[7] = US_(yl); h[8] = US_(zl);
            h[9] = US_(one); h[10] = US_(one);
            h[11] = US_(mnh); h[12] = US_(mnl);
        } else {     // q side
            h[0] = US_(xh); h[1] = US_(yh); h[2] = US_(zh);
            h[3] = US_(xl); h[4] = US_(yl); h[5] = US_(zl);
            h[6] = US_(xh); h[7] = US_(yh); h[8] = US_(zh);
            h[9] = US_(mnh); h[10] = US_(mnl);
            h[11] = US_(one); h[12] = US_(one);
        }
#undef US_
        unsigned short* dst = (is1 ? paug : qaug) + (size_t)r * 32;
#pragma unroll
        for (int i = 0; i < 4; i++) ((uint4*)dst)[i] = ((const uint4*)h)[i];
    }
}

// ---------------------------------------------------------------------------
// Kernel 2: MFMA cosine-sim GEMM (asymmetric fp16 2-term: hA*(hB+lB)) +
// w2 via augmented-coord MFMA + h-paired pk-f32 MLP.  BK=32 double-buffered,
// 2-phase prefetch.  NEW: epilogue stores bounced through LDS so each
// half-wave writes 512 B contiguous (4 full cache lines) — kills the
// partial-line write-allocate traffic (R7: WRITE 177 vs 134 mandatory).
// ---------------------------------------------------------------------------
__global__ __launch_bounds__(256, 3)
void gemm_mlp_kernel(const unsigned short* __restrict__ aH0,  // f2 hi (A, q)
                     const unsigned short* __restrict__ bH0,  // f1 hi (B, p)
                     const unsigned short* __restrict__ bL0,  // f1 lo (B, p)
                     const unsigned short* __restrict__ qaug,
                     const unsigned short* __restrict__ paug,
                     const float* __restrict__ pW1, const float* __restrict__ pb1,
                     const float* __restrict__ pW2, const float* __restrict__ pb2,
                     float* __restrict__ w_out) {
    // 2 buffers x 3 tiles (Ahi | Bhi | Blo) x 8 KiB = 48 KiB
    // (reused as float[64][128] = 32 KiB output bounce in the epilogue)
    __shared__ unsigned short ldsbuf[2 * 3 * 4096];

    int tid = threadIdx.x;
    // bijective XCD chunking swizzle within each z-slice (256 blocks, 256%8==0)
    int l  = blockIdx.x + (blockIdx.y << 4);
    int ls = ((l & 7) << 5) | (l >> 3);
    int pBase = (ls & 15) * BM;
    int qBase = (ls >> 4) * BM;
    int b = blockIdx.z;

    int lane = tid & 63;
    int wv   = tid >> 6;
    int wq = (wv >> 1) * 64;
    int wp = (wv & 1) * 64;
    int fr = lane & 15;
    int kg = lane >> 4;

    const int Apanel8 = ((b * N_ + qBase) >> 7) * 8;   // 8 KiB tile idx base
    const int Bpanel8 = ((b * N_ + pBase) >> 7) * 8;

    char* ldsB = (char*)&ldsbuf[0];
    const int wlo = (wv << 11) + (lane << 4);   // per-lane global byte offset
    const int wdo = (wv << 11);                 // wave-uniform LDS byte offset
    const int cw  = (kg ^ ((fr >> 1) & 3)) << 4;  // swizzled 16B slot

    f32x4 acc[4][4] = {};

#define STAGE(buf, c)                                                          \
    {                                                                          \
        const char* aH = (const char*)aH0 + ((size_t)(Apanel8 + (c)) << 13);   \
        const char* bH = (const char*)bH0 + ((size_t)(Bpanel8 + (c)) << 13);   \
        const char* bL = (const char*)bL0 + ((size_t)(Bpanel8 + (c)) << 13);   \
        char* dst = ldsB + (buf) * 24576;                                      \
        _Pragma("unroll")                                                      \
        for (int i = 0; i < 2; i++) {                                          \
            int o = i << 10;                                                   \
            g2l16(aH + wlo + o, dst + 0     + wdo + o);                        \
            g2l16(bH + wlo + o, dst + 8192  + wdo + o);                        \
            g2l16(bL + wlo + o, dst + 16384 + wdo + o);                        \
        }                                                                      \
    }

    STAGE(0, 0);
    __syncthreads();                       // drain: buf0 ready

#pragma unroll
    for (int c = 0; c < 8; c++) {          // 8 K-chunks of 32
        if (c < 7) STAGE((c + 1) & 1, c + 1);   // prefetch next (other buffer)

        char* base = ldsB + (c & 1) * 24576;
        f16x8 ah[4], bh[4], bl[4];
#pragma unroll
        for (int t = 0; t < 4; t++) {
            int ra = (wq + t * 16 + fr) * 64;
            int rb = (wp + t * 16 + fr) * 64;
            ah[t] = *(const f16x8*)(base + 0     + ra + cw);
            bh[t] = *(const f16x8*)(base + 8192  + rb + cw);
            bl[t] = *(const f16x8*)(base + 16384 + rb + cw);
        }
#pragma unroll
        for (int qt = 0; qt < 4; qt++) {
#pragma unroll
            for (int pt = 0; pt < 4; pt++) {
                acc[qt][pt] = __builtin_amdgcn_mfma_f32_16x16x32_f16(
                    ah[qt], bh[pt], acc[qt][pt], 0, 0, 0);
                acc[qt][pt] = __builtin_amdgcn_mfma_f32_16x16x32_f16(
                    ah[qt], bl[pt], acc[qt][pt], 0, 0, 0);
            }
        }
        __syncthreads();   // drains prefetch vmcnt + all waves done with buf
    }
#undef STAGE

    // ---------------- epilogue: w2 MFMA + h-paired MLP -> LDS -> coalesced
    // stores (two 64-row halves; 32 KiB bounce buffer) ---------------------
    f32x2 Wap[8], Wbp[8], Bbp[8], Wop[8];
#pragma unroll
    for (int hp = 0; hp < 8; hp++) {
        Wap[hp] = (f32x2){pW1[4 * hp],     pW1[4 * hp + 2]};
        Wbp[hp] = (f32x2){pW1[4 * hp + 1], pW1[4 * hp + 3]};
        Bbp[hp] = (f32x2){pb1[2 * hp],     pb1[2 * hp + 1]};
        Wop[hp] = (f32x2){pW2[2 * hp],     pW2[2 * hp + 1]};
    }
    float b2v = pb2[0];

    const unsigned short* qa_base = qaug + ((size_t)(b * N_ + qBase + wq) << 5) + kg * 8;
    const unsigned short* pa_base = paug + ((size_t)(b * N_ + pBase + wp) << 5) + kg * 8;

    float* ldsw = (float*)&ldsbuf[0];
    float* wbase = w_out + (size_t)(b * N_ + qBase) * N_ + pBase;
    int c4 = (tid & 31) << 2;            // writer: float4 col within 128
    int r0 = tid >> 5;                   // writer: row 0..7 (half-wave per row)

#pragma unroll
    for (int hf = 0; hf < 2; hf++) {     // two 64-row halves (qt pairs)
        if (hf) __syncthreads();         // LDS reuse guard (half 0 safe: main
                                         // loop ended with __syncthreads)
#pragma unroll
        for (int qt2 = 0; qt2 < 2; qt2++) {
            int qt = 2 * hf + qt2;
            f16x8 aaug = *(const f16x8*)(qa_base + ((qt * 16 + fr) << 5));
#pragma unroll
            for (int pt = 0; pt < 4; pt++) {
                f16x8 baug = *(const f16x8*)(pa_base + ((pt * 16 + fr) << 5));
                f32x4 sacc = __builtin_amdgcn_mfma_f32_16x16x32_f16(
                    aaug, baug, (f32x4){0.f, 0.f, 0.f, 0.f}, 0, 0, 0);
                f32x4 cval = acc[qt][pt];
                int Lp = wp + pt * 16 + fr;
                int LpS = Lp ^ (kg << 4);          // bank swizzle (2-way=free)
#pragma unroll
                for (int r = 0; r < 4; r++) {
                    float w1 = cval[r];
                    float w2 = fminf(sacc[r], 0.f);   // = -max(d2, 0)
                    f32x2 w1p = {w1, w1}, w2p = {w2, w2};
                    f32x2 o = {b2v, 0.f};
#pragma unroll
                    for (int hp = 0; hp < 8; hp++) {
                        f32x2 t = __builtin_elementwise_fma(w2p, Wbp[hp], Bbp[hp]);
                        t = __builtin_elementwise_fma(w1p, Wap[hp], t);
                        t = __builtin_elementwise_max(t, (f32x2){0.f, 0.f});
                        o = __builtin_elementwise_fma(t, Wop[hp], o);
                    }
                    int Lq = ((wv >> 1) << 5) + (qt2 << 4) + (kg << 2) + r;
                    ldsw[Lq * 128 + LpS] = o.x + o.y;
                }
            }
        }
        __syncthreads();
        // write 64 rows x 512B; half-wave per row -> fully coalesced lines
#pragma unroll
        for (int it = 0; it < 8; it++) {
            int Lq  = r0 + (it << 3);                    // 0..63
            int kgr = (Lq >> 2) & 3;                     // matches writer's kg
            float4 v = *(float4*)&ldsw[Lq * 128 + (c4 ^ (kgr << 4))];
            int row_off = ((Lq >> 5) << 6) + (hf << 5) + (Lq & 31);
            *(float4*)&wbase[row_off * N_ + c4] = v;
        }
    }
}

// ---------------------------------------------------------------------------
// Kernel 3: threshold candidate select -> exact fp64 rescore (ILP partial
// sums, precomputed norms both sides) -> exact top-8 via LDS rank (bounded
// by ncand) -> softmax + gather + pool.  (unchanged from round 7 — verified)
// ---------------------------------------------------------------------------
__global__ __launch_bounds__(256)
void topk_kernel(const float* __restrict__ w, const float* __restrict__ f1,
                 const float* __restrict__ f2,
                 const float* __restrict__ pc, const float* __restrict__ qc,
                 const float* __restrict__ pW1, const float* __restrict__ pb1,
                 const float* __restrict__ pW2, const float* __restrict__ pb2,
                 const double* __restrict__ dinv1, const double* __restrict__ dinv2,
                 float* __restrict__ f_out, float* __restrict__ idx_out) {
    __shared__ int    s_cand[4][POOL];
    __shared__ double s_val[4][POOL];
    __shared__ int    s_idx[4][POOL];
    __shared__ double s_rv[4][K_];
    __shared__ int    s_ri[4][K_];

    int tid  = threadIdx.x;
    int wix  = tid >> 6;
    int lane = tid & 63;
    int row  = blockIdx.x * 4 + wix;          // grid is exact: row < B_*N_
    int b    = row >> 11;
    const float* wrow = w + (size_t)row * N_;

    // ---- phase 1: vector scan, per-lane max only ----
    float4 v4s[8];
    float mymax = -INFINITY;
#pragma unroll
    for (int j = 0; j < 8; j++) {
        v4s[j] = *(const float4*)(wrow + lane * 4 + j * 256);
        mymax = fmaxf(mymax,
                 fmaxf(fmaxf(v4s[j].x, v4s[j].y), fmaxf(v4s[j].z, v4s[j].w)));
    }

    // ---- phase 2a: T = PSEL-th largest of the 64 lane-maxes ----
    unsigned mk = ford(mymax);
    unsigned T = 0;
    for (int bit = 31; bit >= 0; --bit) {
        unsigned c = T | (1u << bit);
        if (__popcll(__ballot(mk >= c)) >= PSEL) T = c;
    }
    float Tf = unford(T);

    // ---- phase 2b: ballot prefix compaction of {v >= Tf} ----
    unsigned long long below = (1ull << lane) - 1ull;
    int total = 0;
#pragma unroll
    for (int j = 0; j < 8; j++) {
        float vv[4] = {v4s[j].x, v4s[j].y, v4s[j].z, v4s[j].w};
#pragma unroll
        for (int c = 0; c < 4; c++) {
            bool in = vv[c] >= Tf;
            unsigned long long m = __ballot(in);
            if (in) {
                int pos = total + __popcll(m & below);
                if (pos < POOL) s_cand[wix][pos] = lane * 4 + j * 256 + c;
            }
            total += __popcll(m);
        }
    }
    int ncand = total < POOL ? total : POOL;   // always >= PSEL = 16 > K_
    asm volatile("s_waitcnt lgkmcnt(0)" ::: "memory");   // in-wave LDS drain

    // ---- phase 3: parallel exact fp64 rescore (norms precomputed) ----
    int sl = lane & 7;
    int gr = lane >> 3;
    const float* f2r = f2 + ((size_t)row << 8) + sl * 32;
    float4 a4[8];
#pragma unroll
    for (int t = 0; t < 8; t++) a4[t] = *(const float4*)(f2r + t * 4);

    double inv_a;
    if (dinv2) {
        inv_a = dinv2[row];
    } else {
        double daa = 0.0;
#pragma unroll
        for (int t = 0; t < 8; t++) {
            daa += (double)a4[t].x * (double)a4[t].x;
            daa += (double)a4[t].y * (double)a4[t].y;
            daa += (double)a4[t].z * (double)a4[t].z;
            daa += (double)a4[t].w * (double)a4[t].w;
        }
#pragma unroll
        for (int off = 1; off < 8; off <<= 1) daa += __shfl_xor(daa, off, 64);
        inv_a = 1.0 / (sqrt(daa) + 1e-8);
    }

    const float* f1bb = f1 + ((size_t)(b * N_) << 8);
    double mydab = 0.0;
    int myci = 0;
    int NR = (ncand + 7) >> 3;               // typically 2-3 (wave-uniform)
    for (int r = 0; r < NR; r++) {
        int k = 8 * r + gr;
        int cj = (k < ncand) ? s_cand[wix][k] : 0;
        const float* f1r = f1bb + ((unsigned)(cj << 8)) + sl * 32;
        double ps0 = 0.0, ps1 = 0.0, ps2 = 0.0, ps3 = 0.0;   // 4-way ILP
#pragma unroll
        for (int t = 0; t < 8; t += 4) {
            float4 b0 = *(const float4*)(f1r + t * 4);
            float4 b1 = *(const float4*)(f1r + t * 4 + 4);
            float4 b2 = *(const float4*)(f1r + t * 4 + 8);
            float4 b3 = *(const float4*)(f1r + t * 4 + 12);
            ps0 += (double)a4[t].x * b0.x + (double)a4[t].y * b0.y
                 + (double)a4[t].z * b0.z + (double)a4[t].w * b0.w;
            ps1 += (double)a4[t+1].x * b1.x + (double)a4[t+1].y * b1.y
                 + (double)a4[t+1].z * b1.z + (double)a4[t+1].w * b1.w;
            ps2 += (double)a4[t+2].x * b2.x + (double)a4[t+2].y * b2.y
                 + (double)a4[t+2].z * b2.z + (double)a4[t+2].w * b2.w;
            ps3 += (double)a4[t+3].x * b3.x + (double)a4[t+3].y * b3.y
                 + (double)a4[t+3].z * b3.z + (double)a4[t+3].w * b3.w;
        }
        double sA = (ps0 + ps1) + (ps2 + ps3);
#pragma unroll
        for (int off = 1; off < 8; off <<= 1) sA += __shfl_xor(sA, off, 64);
        if (sl == r) { mydab = sA; myci = cj; }
    }

    // lane (gr, sl) owns candidate k = 8*sl + gr
    int myk = 8 * sl + gr;
    double ex = -INFINITY;
    int    ei = 0x7fffffff;
    if (myk < ncand) {
        ei = myci;
        double w1d = mydab * inv_a * dinv1[b * N_ + myci];
        const float* qp = qc + (size_t)row * 3;
        double qx = qp[0], qy = qp[1], qz = qp[2];
        const float* pp = pc + ((size_t)(b * N_ + myci)) * 3;
        double px = pp[0], py = pp[1], pz = pp[2];
        double d2 = (qx * qx + qy * qy + qz * qz) + (px * px + py * py + pz * pz)
                  - 2.0 * (qx * px + qy * py + qz * pz);
        double w2d = -fmax(d2, 0.0);
        double out = (double)pb2[0];
#pragma unroll
        for (int h = 0; h < H_; h++) {
            double t = (double)pW1[2 * h] * w1d + (double)pW1[2 * h + 1] * w2d
                     + (double)pb1[h];
            out += (double)pW2[h] * fmax(t, 0.0);
        }
        ex = out;
    }

    // ---- phase 4: exact top-8 via LDS rank (desc, smaller idx tie) ----
    s_val[wix][myk] = ex;
    s_idx[wix][myk] = ei;
    asm volatile("s_waitcnt lgkmcnt(0)" ::: "memory");   // in-wave LDS drain
    {
        int rank = 0;
        for (int j = 0; j < ncand; j++) {
            double vj = s_val[wix][j];
            int    ij = s_idx[wix][j];
            rank += (vj > ex || (vj == ex && ij < ei)) ? 1 : 0;
        }
        if (rank < K_ && myk < ncand) { s_rv[wix][rank] = ex; s_ri[wix][rank] = ei; }
    }
    asm volatile("s_waitcnt lgkmcnt(0)" ::: "memory");   // in-wave LDS drain

    double outv[K_];
    int    outi[K_];
#pragma unroll
    for (int r = 0; r < K_; r++) { outv[r] = s_rv[wix][r]; outi[r] = s_ri[wix][r]; }

    // ---- phase 5: softmax + gather + pool + write ----
    float m = (float)outv[0];
    float e[K_], s = 0.f;
#pragma unroll
    for (int r = 0; r < K_; r++) { e[r] = expf((float)outv[r] - m); s += e[r]; }
    float inv_s = 1.f / s;

    const float* f1b = f1 + ((size_t)b * N_) * D_;
    size_t obase = (size_t)row * (2 * D_);
#pragma unroll
    for (int jd = 0; jd < D_ / 64; jd++) {
        int d = lane + 64 * jd;
        float accv = 0.f, mx = -INFINITY;
#pragma unroll
        for (int r = 0; r < K_; r++) {
            float x = f1b[(size_t)outi[r] * D_ + d];
            accv += (e[r] * inv_s) * x;
            mx = fmaxf(mx, x);
        }
        f_out[obase + d]      = accv;
        f_out[obase + D_ + d] = mx;
    }
    if (lane == 0) {
#pragma unroll
        for (int r = 0; r < K_; r++) idx_out[(size_t)row * K_ + r] = (float)outi[r];
    }
}

// ---------------------------------------------------------------------------
extern "C" void kernel_launch(void* const* d_in, const int* in_sizes, int n_in,
                              void* d_out, int out_size, void* d_ws, size_t ws_size,
                              hipStream_t stream) {
    const float* f1 = (const float*)d_in[0];
    const float* f2 = (const float*)d_in[1];
    const float* pc = (const float*)d_in[2];
    const float* qc = (const float*)d_in[3];
    const float* W1 = (const float*)d_in[4];
    const float* b1 = (const float*)d_in[5];
    const float* W2 = (const float*)d_in[6];
    const float* b2 = (const float*)d_in[7];

    float* out     = (float*)d_out;
    float* f_out   = out;                                   // [B,N,2D]
    float* idx_out = f_out + (size_t)B_ * N_ * 2 * D_;      // [B,N,K] as float
    float* w_out   = idx_out + (size_t)B_ * N_ * K_;        // [B,N,N]

    // Scratch in the f_out region (33,554,432 B): 3 fp16 panels (25.2 MB) +
    // 2 augmented coord arrays (2 x 1 MB).  f_out is only written by
    // topk_kernel afterwards, so this is safe under stream ordering.
    unsigned short* s1h  = (unsigned short*)f_out;          // f1 hi (B side)
    unsigned short* s1l  = s1h + (size_t)B_ * N_ * D_;      // f1 lo (B side)
    unsigned short* s2h  = s1l + (size_t)B_ * N_ * D_;      // f2 hi (A side)
    unsigned short* qaug = s2h + (size_t)B_ * N_ * D_;      // [B*N][32] fp16
    unsigned short* paug = qaug + (size_t)B_ * N_ * 32;     // [B*N][32] fp16

    // fp64 inverse norms in d_ws: dinv1 always (128 KiB); dinv2 only if the
    // workspace is large enough (topk has an exact in-kernel fallback).
    double* dinv1 = (double*)d_ws;
    double* dinv2 = (ws_size >= (size_t)2 * B_ * N_ * sizeof(double))
                  ? dinv1 + (size_t)B_ * N_ : nullptr;

    prep_kernel<<<(2 * B_ * N_) / 4, 256, 0, stream>>>(f1, f2, pc, qc,
                                                       s1h, s1l, s2h,
                                                       qaug, paug, dinv1, dinv2);

    dim3 g2(N_ / BM, N_ / BM, B_);
    gemm_mlp_kernel<<<g2, 256, 0, stream>>>(s2h, s1h, s1l, qaug, paug,
                                            W1, b1, W2, b2, w_out);

    topk_kernel<<<(B_ * N_) / 4, 256, 0, stream>>>(w_out, f1, f2, pc, qc,
                                                   W1, b1, W2, b2, dinv1, dinv2,
                                                   f_out, idx_out);
}